// Round 14
// baseline (320.737 us; speedup 1.0000x reference)
//
#include <hip/hip_runtime.h>
#include <hip/hip_fp16.h>
#include <math.h>

#define NNODES 50000
#define NEDGES 100000
#define HID 128
#define NKEYS (NEDGES + NNODES)  // edge keys then node keys

// bucket decomposition: 256 keys per bucket
#define NB_E ((NEDGES + 255) >> 8)  // 391
#define NB_N ((NNODES + 255) >> 8)  // 196
#define NB (NB_E + NB_N)            // 587
#define CAP_E 3072                  // staging capacity per edge bucket
#define CAP_N 6144                  // staging capacity per node bucket
#define PART_CHUNK 1024

__device__ __forceinline__ int region_start(int b) {
  return (b < NB_E) ? b * CAP_E : NB_E * CAP_E + (b - NB_E) * CAP_N;
}

// ===========================================================================
// partition: per-block LDS hist -> reserve in fixed-capacity bucket regions
// item.x = (key_low8 << 18) | neighbor(17b), item.y = val bits
// bucket_cur (zero-init) accumulates per-bucket counts.
// ===========================================================================
__global__ __launch_bounds__(256) void partition_kernel(
    const int* __restrict__ rows, const int* __restrict__ cols,
    const float* __restrict__ vals, int* __restrict__ bucket_cur,
    int2* __restrict__ bkt_items, int nnz) {
  __shared__ int cnt[NB];
  __shared__ int wbase[NB];
  for (int k = threadIdx.x; k < NB; k += 256) cnt[k] = 0;
  __syncthreads();
  int start = blockIdx.x * PART_CHUNK;
  int end = start + PART_CHUNK;
  if (end > nnz) end = nnz;
  for (int i = start + threadIdx.x; i < end; i += 256) {
    atomicAdd(&cnt[cols[i] >> 8], 1);
    atomicAdd(&cnt[NB_E + (rows[i] >> 8)], 1);
  }
  __syncthreads();
  for (int k = threadIdx.x; k < NB; k += 256) {
    int c = cnt[k];
    wbase[k] = c ? region_start(k) + atomicAdd(&bucket_cur[k], c) : 0;
    cnt[k] = 0;
  }
  __syncthreads();
  for (int i = start + threadIdx.x; i < end; i += 256) {
    int c = cols[i], r = rows[i];
    int v = __float_as_int(vals[i]);
    int be = c >> 8;
    int p = wbase[be] + atomicAdd(&cnt[be], 1);
    bkt_items[p] = make_int2(((c & 255) << 18) | r, v);
    int bn = NB_E + (r >> 8);
    int q = wbase[bn] + atomicAdd(&cnt[bn], 1);
    bkt_items[q] = make_int2(((r & 255) << 18) | c, v);
  }
}

// exclusive scan of NB bucket counts -> dense bases. one block.
__global__ __launch_bounds__(1024) void bucket_scan_kernel(
    const int* __restrict__ bucket_cur, int* __restrict__ bucket_base) {
  int t = threadIdx.x;
  int lane = t & 63, wid = t >> 6;
  int x = (t < NB) ? bucket_cur[t] : 0;
  int incl = x;
#pragma unroll
  for (int d = 1; d < 64; d <<= 1) {
    int tt = __shfl_up(incl, d, 64);
    if (lane >= d) incl += tt;
  }
  __shared__ int ws[16];
  if (lane == 63) ws[wid] = incl;
  __syncthreads();
  int woff = 0;
  for (int k = 0; k < wid; ++k) woff += ws[k];
  int excl = woff + incl - x;
  if (t < NB) bucket_base[t] = excl;
  if (t == NB - 1) bucket_base[NB] = excl + x;  // == 2*nnz
}

// ===========================================================================
// place: one block per bucket; reads its staged region, per-key LDS
// hist+scan (+ fused degree sums); writes dense off[], pair[], dein/dvis.
// ===========================================================================
__global__ __launch_bounds__(256) void place_kernel(
    const int* __restrict__ bucket_base, const int* __restrict__ bucket_cur,
    const int2* __restrict__ bkt_items, int* __restrict__ off,
    int2* __restrict__ pair, float* __restrict__ dein,
    float* __restrict__ dvis) {
  int b = blockIdx.x;
  int rs = region_start(b);
  int cntb = bucket_cur[b];
  int s = bucket_base[b];
  __shared__ int kcnt[256];
  __shared__ float ksum[256];
  __shared__ int kbase[256];
  __shared__ int ws[4];
  int t = threadIdx.x;
  kcnt[t] = 0;
  ksum[t] = 0.f;
  __syncthreads();
  for (int j = rs + t; j < rs + cntb; j += 256) {
    int2 it = bkt_items[j];
    int k = it.x >> 18;
    atomicAdd(&kcnt[k], 1);
    atomicAdd(&ksum[k], __int_as_float(it.y));
  }
  __syncthreads();
  int x = kcnt[t];
  int lane = t & 63, wid = t >> 6;
  int incl = x;
#pragma unroll
  for (int d = 1; d < 64; d <<= 1) {
    int tt = __shfl_up(incl, d, 64);
    if (lane >= d) incl += tt;
  }
  if (lane == 63) ws[wid] = incl;
  __syncthreads();
  int woff = 0;
  for (int k = 0; k < wid; ++k) woff += ws[k];
  int excl = woff + incl - x;
  kbase[t] = s + excl;
  float sum = fmaxf(ksum[t], 1e-6f);
  if (b < NB_E) {
    int kglob = (b << 8) | t;
    if (kglob < NEDGES) {
      off[kglob] = s + excl;
      dein[kglob] = 1.0f / sum;
    }
  } else {
    int kglob = ((b - NB_E) << 8) | t;
    if (kglob < NNODES) {
      off[NEDGES + kglob] = s + excl;
      dvis[kglob] = rsqrtf(sum);
    }
  }
  if (b == NB - 1 && t == 0) off[NKEYS] = s + cntb;
  __syncthreads();
  kcnt[t] = 0;
  __syncthreads();
  for (int j = rs + t; j < rs + cntb; j += 256) {
    int2 it = bkt_items[j];
    int k = it.x >> 18;
    int pos = kbase[k] + atomicAdd(&kcnt[k], 1);
    pair[pos] = make_int2(it.x & 0x3FFFF, it.y);
  }
}

// ===========================================================================
// scalex_h: Xh (fp16 row-major) = dvis * X0. One thread per float4 (4 elems).
// ===========================================================================
__global__ __launch_bounds__(256) void scalex_h_kernel(
    const float* __restrict__ X, const float* __restrict__ dvis,
    uint2* __restrict__ Yh) {
  int i = blockIdx.x * 256 + threadIdx.x;
  if (i >= NNODES * 32) return;
  float s = dvis[i >> 5];
  float4 v = reinterpret_cast<const float4*>(X)[i];
  __half2 a = __float22half2_rn(make_float2(s * v.x, s * v.y));
  __half2 b = __float22half2_rn(make_float2(s * v.z, s * v.w));
  uint2 o;
  o.x = *reinterpret_cast<unsigned*>(&a);
  o.y = *reinterpret_cast<unsigned*>(&b);
  Yh[i] = o;
}

// ===========================================================================
// gather v7 (fp16): ONE SEGMENT PER 16-LANE GROUP (4 segments/wave).
// Group's 16 lanes read the full 256 B fp16 row as uint4; 2-deep unroll
// keeps 2 rows/group (8/wave) in flight. fp32 accumulate; NO cross-group
// shuffles; all 16 lanes write the output row directly.
// ===========================================================================
__global__ __launch_bounds__(256) void gather_hh_kernel(
    const uint4* __restrict__ src, uint4* __restrict__ dst,
    const int* __restrict__ off, const int2* __restrict__ pair,
    const float* __restrict__ seg_scale, int nseg) {
  int e = blockIdx.x * 16 + (threadIdx.x >> 4);
  if (e >= nseg) return;
  int li = threadIdx.x & 15;
  int s = off[e], t = off[e + 1];
  float acc[8] = {0.f, 0.f, 0.f, 0.f, 0.f, 0.f, 0.f, 0.f};
  int j = s;
  for (; j + 1 < t; j += 2) {
    int2 p0 = pair[j], p1 = pair[j + 1];
    float w0 = __int_as_float(p0.y), w1 = __int_as_float(p1.y);
    uint4 u0 = src[(size_t)p0.x * 16 + li];
    uint4 u1 = src[(size_t)p1.x * 16 + li];
    float2 f0 = __half22float2(*reinterpret_cast<__half2*>(&u0.x));
    float2 f1 = __half22float2(*reinterpret_cast<__half2*>(&u0.y));
    float2 f2 = __half22float2(*reinterpret_cast<__half2*>(&u0.z));
    float2 f3 = __half22float2(*reinterpret_cast<__half2*>(&u0.w));
    acc[0] = fmaf(w0, f0.x, acc[0]); acc[1] = fmaf(w0, f0.y, acc[1]);
    acc[2] = fmaf(w0, f1.x, acc[2]); acc[3] = fmaf(w0, f1.y, acc[3]);
    acc[4] = fmaf(w0, f2.x, acc[4]); acc[5] = fmaf(w0, f2.y, acc[5]);
    acc[6] = fmaf(w0, f3.x, acc[6]); acc[7] = fmaf(w0, f3.y, acc[7]);
    float2 g0 = __half22float2(*reinterpret_cast<__half2*>(&u1.x));
    float2 g1 = __half22float2(*reinterpret_cast<__half2*>(&u1.y));
    float2 g2 = __half22float2(*reinterpret_cast<__half2*>(&u1.z));
    float2 g3 = __half22float2(*reinterpret_cast<__half2*>(&u1.w));
    acc[0] = fmaf(w1, g0.x, acc[0]); acc[1] = fmaf(w1, g0.y, acc[1]);
    acc[2] = fmaf(w1, g1.x, acc[2]); acc[3] = fmaf(w1, g1.y, acc[3]);
    acc[4] = fmaf(w1, g2.x, acc[4]); acc[5] = fmaf(w1, g2.y, acc[5]);
    acc[6] = fmaf(w1, g3.x, acc[6]); acc[7] = fmaf(w1, g3.y, acc[7]);
  }
  if (j < t) {
    int2 p0 = pair[j];
    float w0 = __int_as_float(p0.y);
    uint4 u0 = src[(size_t)p0.x * 16 + li];
    float2 f0 = __half22float2(*reinterpret_cast<__half2*>(&u0.x));
    float2 f1 = __half22float2(*reinterpret_cast<__half2*>(&u0.y));
    float2 f2 = __half22float2(*reinterpret_cast<__half2*>(&u0.z));
    float2 f3 = __half22float2(*reinterpret_cast<__half2*>(&u0.w));
    acc[0] = fmaf(w0, f0.x, acc[0]); acc[1] = fmaf(w0, f0.y, acc[1]);
    acc[2] = fmaf(w0, f1.x, acc[2]); acc[3] = fmaf(w0, f1.y, acc[3]);
    acc[4] = fmaf(w0, f2.x, acc[4]); acc[5] = fmaf(w0, f2.y, acc[5]);
    acc[6] = fmaf(w0, f3.x, acc[6]); acc[7] = fmaf(w0, f3.y, acc[7]);
  }
  float sc = seg_scale ? seg_scale[e] : 1.0f;
  __half2 h0 = __float22half2_rn(make_float2(sc * acc[0], sc * acc[1]));
  __half2 h1 = __float22half2_rn(make_float2(sc * acc[2], sc * acc[3]));
  __half2 h2 = __float22half2_rn(make_float2(sc * acc[4], sc * acc[5]));
  __half2 h3 = __float22half2_rn(make_float2(sc * acc[6], sc * acc[7]));
  uint4 o;
  o.x = *reinterpret_cast<unsigned*>(&h0);
  o.y = *reinterpret_cast<unsigned*>(&h1);
  o.z = *reinterpret_cast<unsigned*>(&h2);
  o.w = *reinterpret_cast<unsigned*>(&h3);
  dst[(size_t)e * 16 + li] = o;
}

// ===========================================================================
// GEMM (fp16 X rows): acc = Pnh[n,:] @ W^T[:, j0:j0+64]
// Pnh already carries the propagate dvis scale (node-gather epilogue).
// mode 0: acc -> fp32 d_out | mode 1: dvis*relu(acc) -> fp16 Xh (layer2 src)
// ===========================================================================
__device__ __forceinline__ void cvt8(uint4 u, float* f) {
  float2 a = __half22float2(*reinterpret_cast<__half2*>(&u.x));
  float2 b = __half22float2(*reinterpret_cast<__half2*>(&u.y));
  float2 c = __half22float2(*reinterpret_cast<__half2*>(&u.z));
  float2 d = __half22float2(*reinterpret_cast<__half2*>(&u.w));
  f[0] = a.x; f[1] = a.y; f[2] = b.x; f[3] = b.y;
  f[4] = c.x; f[5] = c.y; f[6] = d.x; f[7] = d.y;
}

__global__ __launch_bounds__(256) void gemm_h_kernel(
    const uint4* __restrict__ Pnh, const float* __restrict__ dvis,
    const float* __restrict__ W, void* __restrict__ out_v, int mode) {
  __shared__ float WT[128 * 64];  // 32 KB
  int t = threadIdx.x;
  int jb = blockIdx.x & 1;
  int rb = blockIdx.x >> 1;
  int j0 = jb << 6;
  {
    int K = t & 31;
    int Jb = t >> 5;
#pragma unroll
    for (int p = 0; p < 2; ++p) {
      int J = Jb + (p << 3);
      const float* Wb = W + (size_t)(j0 + 4 * J) * 128 + 4 * K;
      float4 g0 = *reinterpret_cast<const float4*>(Wb);
      float4 g1 = *reinterpret_cast<const float4*>(Wb + 128);
      float4 g2 = *reinterpret_cast<const float4*>(Wb + 256);
      float4 g3 = *reinterpret_cast<const float4*>(Wb + 384);
      const float* g0p = reinterpret_cast<const float*>(&g0);
      const float* g1p = reinterpret_cast<const float*>(&g1);
      const float* g2p = reinterpret_cast<const float*>(&g2);
      const float* g3p = reinterpret_cast<const float*>(&g3);
#pragma unroll
      for (int q = 0; q < 4; ++q) {
        int k = 4 * K + q;
        float4 hq = make_float4(g0p[q], g1p[q], g2p[q], g3p[q]);
        int slot = (J + k) & 15;
        *reinterpret_cast<float4*>(&WT[k * 64 + 4 * slot]) = hq;
      }
    }
  }
  __syncthreads();
  int u = t & 15;
  int rg = t >> 4;
  int rbase = rb * 64 + rg * 4;
  const float4* WT4 = reinterpret_cast<const float4*>(WT);
  float4 acc0 = make_float4(0.f, 0.f, 0.f, 0.f);
  float4 acc1 = acc0, acc2 = acc0, acc3 = acc0;
  int rr0 = rbase + 0; if (rr0 >= NNODES) rr0 = NNODES - 1;
  int rr1 = rbase + 1; if (rr1 >= NNODES) rr1 = NNODES - 1;
  int rr2 = rbase + 2; if (rr2 >= NNODES) rr2 = NNODES - 1;
  int rr3 = rbase + 3; if (rr3 >= NNODES) rr3 = NNODES - 1;
  const uint4* X0 = Pnh + (size_t)rr0 * 16;
  const uint4* X1 = Pnh + (size_t)rr1 * 16;
  const uint4* X2 = Pnh + (size_t)rr2 * 16;
  const uint4* X3 = Pnh + (size_t)rr3 * 16;
#pragma unroll 4
  for (int kk = 0; kk < 16; ++kk) {
    float x0f[8], x1f[8], x2f[8], x3f[8];
    cvt8(X0[kk], x0f);
    cvt8(X1[kk], x1f);
    cvt8(X2[kk], x2f);
    cvt8(X3[kk], x3f);
#pragma unroll
    for (int q = 0; q < 8; ++q) {
      int k = kk * 8 + q;
      float4 w4 = WT4[k * 16 + ((u + k) & 15)];
      acc0.x = fmaf(x0f[q], w4.x, acc0.x); acc0.y = fmaf(x0f[q], w4.y, acc0.y);
      acc0.z = fmaf(x0f[q], w4.z, acc0.z); acc0.w = fmaf(x0f[q], w4.w, acc0.w);
      acc1.x = fmaf(x1f[q], w4.x, acc1.x); acc1.y = fmaf(x1f[q], w4.y, acc1.y);
      acc1.z = fmaf(x1f[q], w4.z, acc1.z); acc1.w = fmaf(x1f[q], w4.w, acc1.w);
      acc2.x = fmaf(x2f[q], w4.x, acc2.x); acc2.y = fmaf(x2f[q], w4.y, acc2.y);
      acc2.z = fmaf(x2f[q], w4.z, acc2.z); acc2.w = fmaf(x2f[q], w4.w, acc2.w);
      acc3.x = fmaf(x3f[q], w4.x, acc3.x); acc3.y = fmaf(x3f[q], w4.y, acc3.y);
      acc3.z = fmaf(x3f[q], w4.z, acc3.z); acc3.w = fmaf(x3f[q], w4.w, acc3.w);
    }
  }
#pragma unroll
  for (int m = 0; m < 4; ++m) {
    int r = rbase + m;
    if (r >= NNODES) break;
    float4 a = (m == 0) ? acc0 : (m == 1) ? acc1 : (m == 2) ? acc2 : acc3;
    if (mode == 1) {
      float s = dvis[r];
      float4 o = make_float4(fmaxf(a.x, 0.f) * s, fmaxf(a.y, 0.f) * s,
                             fmaxf(a.z, 0.f) * s, fmaxf(a.w, 0.f) * s);
      __half2 ha = __float22half2_rn(make_float2(o.x, o.y));
      __half2 hb = __float22half2_rn(make_float2(o.z, o.w));
      uint2 ou;
      ou.x = *reinterpret_cast<unsigned*>(&ha);
      ou.y = *reinterpret_cast<unsigned*>(&hb);
      reinterpret_cast<uint2*>(out_v)[(size_t)r * 32 + (j0 >> 2) + u] = ou;
    } else {
      *reinterpret_cast<float4*>(
          &reinterpret_cast<float*>(out_v)[(size_t)r * 128 + j0 + 4 * u]) = a;
    }
  }
}

// ===========================================================================
// Fallback (atomic-scatter, row-major fp32) kernels — unused if ws suffices
// ===========================================================================
__global__ __launch_bounds__(256) void deg_fb_kernel(
    const int* __restrict__ rows, const int* __restrict__ cols,
    const float* __restrict__ vals, float* __restrict__ dv,
    float* __restrict__ de, int nnz) {
  int i = blockIdx.x * 256 + threadIdx.x;
  if (i >= nnz) return;
  float v = vals[i];
  unsafeAtomicAdd(&dv[rows[i]], v);
  unsafeAtomicAdd(&de[cols[i]], v);
}

__global__ __launch_bounds__(256) void inv_kernel(float* __restrict__ dv,
                                                  float* __restrict__ de) {
  int i = blockIdx.x * 256 + threadIdx.x;
  if (i < NNODES) {
    dv[i] = 1.0f / sqrtf(fmaxf(dv[i], 1e-6f));
  } else if (i < NNODES + NEDGES) {
    int j = i - NNODES;
    de[j] = 1.0f / fmaxf(de[j], 1e-6f);
  }
}

__global__ __launch_bounds__(256) void scatter_edge_kernel(
    const float* __restrict__ X, float* __restrict__ Ye,
    const int* __restrict__ rows, const int* __restrict__ cols,
    const float* __restrict__ vals, const float* __restrict__ dvis, int nnz) {
  int g = (blockIdx.x * 256 + threadIdx.x) >> 5;
  int lane = threadIdx.x & 31;
  if (g >= nnz) return;
  int r = rows[g], c = cols[g];
  float s = vals[g] * dvis[r];
  float4 x = reinterpret_cast<const float4*>(X)[(size_t)r * 32 + lane];
  float* dst = Ye + (size_t)c * HID + lane * 4;
  unsafeAtomicAdd(dst + 0, s * x.x);
  unsafeAtomicAdd(dst + 1, s * x.y);
  unsafeAtomicAdd(dst + 2, s * x.z);
  unsafeAtomicAdd(dst + 3, s * x.w);
}

__global__ __launch_bounds__(256) void scatter_node_kernel(
    const float* __restrict__ Ye, float* __restrict__ Yn,
    const int* __restrict__ rows, const int* __restrict__ cols,
    const float* __restrict__ vals, const float* __restrict__ dein, int nnz) {
  int g = (blockIdx.x * 256 + threadIdx.x) >> 5;
  int lane = threadIdx.x & 31;
  if (g >= nnz) return;
  int r = rows[g], c = cols[g];
  float s = vals[g] * dein[c];
  float4 y = reinterpret_cast<const float4*>(Ye)[(size_t)c * 32 + lane];
  float* dst = Yn + (size_t)r * HID + lane * 4;
  unsafeAtomicAdd(dst + 0, s * y.x);
  unsafeAtomicAdd(dst + 1, s * y.y);
  unsafeAtomicAdd(dst + 2, s * y.z);
  unsafeAtomicAdd(dst + 3, s * y.w);
}

// row-major fp32 GEMM for fallback. mode 2: relu(s*acc), mode 0: s*acc
__global__ __launch_bounds__(256) void gemm_rm_kernel(
    const float* __restrict__ Pn, const float* __restrict__ dvis,
    const float* __restrict__ W, float* __restrict__ out, int mode) {
  __shared__ float WT[128 * 64];
  int t = threadIdx.x;
  int jb = blockIdx.x & 1;
  int rb = blockIdx.x >> 1;
  int j0 = jb << 6;
  {
    int K = t & 31;
    int Jb = t >> 5;
#pragma unroll
    for (int p = 0; p < 2; ++p) {
      int J = Jb + (p << 3);
      const float* Wb = W + (size_t)(j0 + 4 * J) * 128 + 4 * K;
      float4 g0 = *reinterpret_cast<const float4*>(Wb);
      float4 g1 = *reinterpret_cast<const float4*>(Wb + 128);
      float4 g2 = *reinterpret_cast<const float4*>(Wb + 256);
      float4 g3 = *reinterpret_cast<const float4*>(Wb + 384);
      const float* g0p = reinterpret_cast<const float*>(&g0);
      const float* g1p = reinterpret_cast<const float*>(&g1);
      const float* g2p = reinterpret_cast<const float*>(&g2);
      const float* g3p = reinterpret_cast<const float*>(&g3);
#pragma unroll
      for (int q = 0; q < 4; ++q) {
        int k = 4 * K + q;
        float4 hq = make_float4(g0p[q], g1p[q], g2p[q], g3p[q]);
        int slot = (J + k) & 15;
        *reinterpret_cast<float4*>(&WT[k * 64 + 4 * slot]) = hq;
      }
    }
  }
  __syncthreads();
  int u = t & 15;
  int rg = t >> 4;
  int rbase = rb * 64 + rg * 4;
  const float4* WT4 = reinterpret_cast<const float4*>(WT);
  float4 acc0 = make_float4(0.f, 0.f, 0.f, 0.f);
  float4 acc1 = acc0, acc2 = acc0, acc3 = acc0;
  int rr0 = rbase + 0; if (rr0 >= NNODES) rr0 = NNODES - 1;
  int rr1 = rbase + 1; if (rr1 >= NNODES) rr1 = NNODES - 1;
  int rr2 = rbase + 2; if (rr2 >= NNODES) rr2 = NNODES - 1;
  int rr3 = rbase + 3; if (rr3 >= NNODES) rr3 = NNODES - 1;
  const float4* X0 = reinterpret_cast<const float4*>(Pn + (size_t)rr0 * 128);
  const float4* X1 = reinterpret_cast<const float4*>(Pn + (size_t)rr1 * 128);
  const float4* X2 = reinterpret_cast<const float4*>(Pn + (size_t)rr2 * 128);
  const float4* X3 = reinterpret_cast<const float4*>(Pn + (size_t)rr3 * 128);
#pragma unroll 4
  for (int kk = 0; kk < 32; ++kk) {
    float4 x0 = X0[kk], x1 = X1[kk], x2 = X2[kk], x3 = X3[kk];
    const float* x0p = reinterpret_cast<const float*>(&x0);
    const float* x1p = reinterpret_cast<const float*>(&x1);
    const float* x2p = reinterpret_cast<const float*>(&x2);
    const float* x3p = reinterpret_cast<const float*>(&x3);
#pragma unroll
    for (int q = 0; q < 4; ++q) {
      int k = 4 * kk + q;
      float4 w4 = WT4[k * 16 + ((u + k) & 15)];
      acc0.x = fmaf(x0p[q], w4.x, acc0.x); acc0.y = fmaf(x0p[q], w4.y, acc0.y);
      acc0.z = fmaf(x0p[q], w4.z, acc0.z); acc0.w = fmaf(x0p[q], w4.w, acc0.w);
      acc1.x = fmaf(x1p[q], w4.x, acc1.x); acc1.y = fmaf(x1p[q], w4.y, acc1.y);
      acc1.z = fmaf(x1p[q], w4.z, acc1.z); acc1.w = fmaf(x1p[q], w4.w, acc1.w);
      acc2.x = fmaf(x2p[q], w4.x, acc2.x); acc2.y = fmaf(x2p[q], w4.y, acc2.y);
      acc2.z = fmaf(x2p[q], w4.z, acc2.z); acc2.w = fmaf(x2p[q], w4.w, acc2.w);
      acc3.x = fmaf(x3p[q], w4.x, acc3.x); acc3.y = fmaf(x3p[q], w4.y, acc3.y);
      acc3.z = fmaf(x3p[q], w4.z, acc3.z); acc3.w = fmaf(x3p[q], w4.w, acc3.w);
    }
  }
#pragma unroll
  for (int m = 0; m < 4; ++m) {
    int r = rbase + m;
    if (r >= NNODES) break;
    float4 a = (m == 0) ? acc0 : (m == 1) ? acc1 : (m == 2) ? acc2 : acc3;
    float s = dvis[r];
    float4 o = make_float4(s * a.x, s * a.y, s * a.z, s * a.w);
    if (mode == 2) {
      o.x = fmaxf(o.x, 0.f); o.y = fmaxf(o.y, 0.f);
      o.z = fmaxf(o.z, 0.f); o.w = fmaxf(o.w, 0.f);
    }
    *reinterpret_cast<float4*>(&out[(size_t)r * 128 + j0 + 4 * u]) = o;
  }
}

// ===========================================================================
extern "C" void kernel_launch(void* const* d_in, const int* in_sizes, int n_in,
                              void* d_out, int out_size, void* d_ws,
                              size_t ws_size, hipStream_t stream) {
  const int* rows = (const int*)d_in[0];
  const int* cols = (const int*)d_in[1];
  const float* vals = (const float*)d_in[2];
  const float* X0 = (const float*)d_in[3];
  const float* W0 = (const float*)d_in[4];
  const float* W1 = (const float*)d_in[5];
  const int nnz = in_sizes[0];
  float* out = (float*)d_out;

  const int gemm_blocks = ((NNODES + 63) / 64) * 2;

  // fp16 CSR-path workspace (4 B elems):
  // pair[2*nnz int2] | Yeh[E*16 uint4] (bkt_items staging alias) |
  // Xh[N*16 uint4] | Pnh[N*16 uint4] | dvis[N] | dein[E] | off[NKEYS+1] |
  // bucket_cur[NB] | bucket_base[NB+1]
  size_t bkt_cap = (size_t)NB_E * CAP_E + (size_t)NB_N * CAP_N;  // entries
  size_t ye_elems = (size_t)NEDGES * 64;
  size_t xh_elems = (size_t)NNODES * 64;
  size_t elems = 4 * (size_t)nnz + ye_elems + 2 * xh_elems + NNODES + NEDGES +
                 (NKEYS + 1) + NB + (NB + 1);
  size_t need = elems * 4;
  bool bkt_fits = 2 * bkt_cap <= ye_elems;  // staging aliases Yeh

  if (ws_size >= need && bkt_fits && (size_t)2 * nnz <= bkt_cap) {
    int2* pair = (int2*)d_ws;
    uint4* Yeh = (uint4*)(pair + 2 * (size_t)nnz);
    int2* bkt_items = (int2*)Yeh;  // preprocessing alias
    uint4* Xh = Yeh + (size_t)NEDGES * 16;
    uint4* Pnh = Xh + (size_t)NNODES * 16;
    float* dvis = (float*)(Pnh + (size_t)NNODES * 16);
    float* dein = dvis + NNODES;
    int* off = (int*)(dein + NEDGES);
    int* bucket_cur = off + NKEYS + 1;
    int* bucket_base = bucket_cur + NB;

    hipMemsetAsync(bucket_cur, 0, NB * sizeof(int), stream);
    partition_kernel<<<(nnz + PART_CHUNK - 1) / PART_CHUNK, 256, 0, stream>>>(
        rows, cols, vals, bucket_cur, bkt_items, nnz);
    bucket_scan_kernel<<<1, 1024, 0, stream>>>(bucket_cur, bucket_base);
    place_kernel<<<NB, 256, 0, stream>>>(bucket_base, bucket_cur, bkt_items,
                                         off, pair, dein, dvis);
    scalex_h_kernel<<<(NNODES * 32 + 255) / 256, 256, 0, stream>>>(
        X0, dvis, (uint2*)Xh);

    const int eg_blocks = (NEDGES + 15) / 16;
    const int ng_blocks = (NNODES + 15) / 16;

    // layer 1
    gather_hh_kernel<<<eg_blocks, 256, 0, stream>>>(Xh, Yeh, off, pair, dein,
                                                    NEDGES);
    gather_hh_kernel<<<ng_blocks, 256, 0, stream>>>(Yeh, Pnh, off + NEDGES,
                                                    pair, dvis, NNODES);
    gemm_h_kernel<<<gemm_blocks, 256, 0, stream>>>(Pnh, dvis, W0, Xh, 1);

    // layer 2
    gather_hh_kernel<<<eg_blocks, 256, 0, stream>>>(Xh, Yeh, off, pair, dein,
                                                    NEDGES);
    gather_hh_kernel<<<ng_blocks, 256, 0, stream>>>(Yeh, Pnh, off + NEDGES,
                                                    pair, dvis, NNODES);
    gemm_h_kernel<<<gemm_blocks, 256, 0, stream>>>(Pnh, dvis, W1, out, 0);
    return;
  }

  // ---------- fallback: fp32 atomic-scatter path (row-major) ----------
  float* dv = (float*)d_ws;
  float* de = dv + NNODES;
  float* Ye = de + NEDGES;
  float* Pn = Ye + (size_t)NEDGES * HID;
  const int scat_blocks = (nnz + 7) / 8;

  hipMemsetAsync(dv, 0, (size_t)(NNODES + NEDGES) * sizeof(float), stream);
  deg_fb_kernel<<<(nnz + 255) / 256, 256, 0, stream>>>(rows, cols, vals, dv,
                                                       de, nnz);
  inv_kernel<<<(NNODES + NEDGES + 255) / 256, 256, 0, stream>>>(dv, de);

  hipMemsetAsync(Ye, 0, (size_t)NEDGES * HID * sizeof(float), stream);
  scatter_edge_kernel<<<scat_blocks, 256, 0, stream>>>(X0, Ye, rows, cols,
                                                       vals, dv, nnz);
  hipMemsetAsync(Pn, 0, (size_t)NNODES * HID * sizeof(float), stream);
  scatter_node_kernel<<<scat_blocks, 256, 0, stream>>>(Ye, Pn, rows, cols,
                                                       vals, de, nnz);
  gemm_rm_kernel<<<gemm_blocks, 256, 0, stream>>>(Pn, dv, W0, out, 2);

  hipMemsetAsync(Ye, 0, (size_t)NEDGES * HID * sizeof(float), stream);
  scatter_edge_kernel<<<scat_blocks, 256, 0, stream>>>(out, Ye, rows, cols,
                                                       vals, dv, nnz);
  hipMemsetAsync(Pn, 0, (size_t)NNODES * HID * sizeof(float), stream);
  scatter_node_kernel<<<scat_blocks, 256, 0, stream>>>(Ye, Pn, rows, cols,
                                                       vals, de, nnz);
  gemm_rm_kernel<<<gemm_blocks, 256, 0, stream>>>(Pn, dv, W1, out, 0);
}

// Round 15
// 295.787 us; speedup vs baseline: 1.0844x; 1.0844x over previous
//
#include <hip/hip_runtime.h>
#include <hip/hip_fp16.h>
#include <math.h>

#define NNODES 50000
#define NEDGES 100000
#define HID 128
#define NKEYS (NEDGES + NNODES)  // edge keys then node keys

// bucket decomposition: 256 keys per bucket
#define NB_E ((NEDGES + 255) >> 8)  // 391
#define NB_N ((NNODES + 255) >> 8)  // 196
#define NB (NB_E + NB_N)            // 587
#define CAP_E 3072                  // staging capacity per edge bucket
#define CAP_N 6144                  // staging capacity per node bucket
#define PART_CHUNK 2048

__device__ __forceinline__ int region_start(int b) {
  return (b < NB_E) ? b * CAP_E : NB_E * CAP_E + (b - NB_E) * CAP_N;
}

// ===========================================================================
// partition: per-block LDS hist -> reserve in fixed-capacity bucket regions
// item.x = (key_low8 << 18) | neighbor(17b), item.y = val bits
// bucket_cur (zero-init) accumulates per-bucket counts.
// ===========================================================================
__global__ __launch_bounds__(256) void partition_kernel(
    const int* __restrict__ rows, const int* __restrict__ cols,
    const float* __restrict__ vals, int* __restrict__ bucket_cur,
    int2* __restrict__ bkt_items, int nnz) {
  __shared__ int cnt[NB];
  __shared__ int wbase[NB];
  for (int k = threadIdx.x; k < NB; k += 256) cnt[k] = 0;
  __syncthreads();
  int start = blockIdx.x * PART_CHUNK;
  int end = start + PART_CHUNK;
  if (end > nnz) end = nnz;
  for (int i = start + threadIdx.x; i < end; i += 256) {
    atomicAdd(&cnt[cols[i] >> 8], 1);
    atomicAdd(&cnt[NB_E + (rows[i] >> 8)], 1);
  }
  __syncthreads();
  for (int k = threadIdx.x; k < NB; k += 256) {
    int c = cnt[k];
    wbase[k] = c ? region_start(k) + atomicAdd(&bucket_cur[k], c) : 0;
    cnt[k] = 0;
  }
  __syncthreads();
  for (int i = start + threadIdx.x; i < end; i += 256) {
    int c = cols[i], r = rows[i];
    int v = __float_as_int(vals[i]);
    int be = c >> 8;
    int p = wbase[be] + atomicAdd(&cnt[be], 1);
    bkt_items[p] = make_int2(((c & 255) << 18) | r, v);
    int bn = NB_E + (r >> 8);
    int q = wbase[bn] + atomicAdd(&cnt[bn], 1);
    bkt_items[q] = make_int2(((r & 255) << 18) | c, v);
  }
}

// exclusive scan of NB bucket counts -> dense bases. one block.
__global__ __launch_bounds__(1024) void bucket_scan_kernel(
    const int* __restrict__ bucket_cur, int* __restrict__ bucket_base) {
  int t = threadIdx.x;
  int lane = t & 63, wid = t >> 6;
  int x = (t < NB) ? bucket_cur[t] : 0;
  int incl = x;
#pragma unroll
  for (int d = 1; d < 64; d <<= 1) {
    int tt = __shfl_up(incl, d, 64);
    if (lane >= d) incl += tt;
  }
  __shared__ int ws[16];
  if (lane == 63) ws[wid] = incl;
  __syncthreads();
  int woff = 0;
  for (int k = 0; k < wid; ++k) woff += ws[k];
  int excl = woff + incl - x;
  if (t < NB) bucket_base[t] = excl;
  if (t == NB - 1) bucket_base[NB] = excl + x;  // == 2*nnz
}

// ===========================================================================
// place v2: one block per bucket; caches staged region in LDS (<= CAP_N
// items = 48 KB), per-key LDS hist+scan (+ fused degree sums); writes dense
// off[], pair[], dein/dvis.
// ===========================================================================
__global__ __launch_bounds__(256) void place_kernel(
    const int* __restrict__ bucket_base, const int* __restrict__ bucket_cur,
    const int2* __restrict__ bkt_items, int* __restrict__ off,
    int2* __restrict__ pair, float* __restrict__ dein,
    float* __restrict__ dvis) {
  __shared__ int2 items[CAP_N];  // 48 KB
  __shared__ int kcnt[256];
  __shared__ float ksum[256];
  __shared__ int kbase[256];
  __shared__ int ws[4];
  int b = blockIdx.x;
  int rs = region_start(b);
  int cntb = bucket_cur[b];
  int s = bucket_base[b];
  int t = threadIdx.x;
  kcnt[t] = 0;
  ksum[t] = 0.f;
  __syncthreads();
  for (int j = t; j < cntb; j += 256) {
    int2 it = bkt_items[rs + j];
    items[j] = it;
    int k = it.x >> 18;
    atomicAdd(&kcnt[k], 1);
    atomicAdd(&ksum[k], __int_as_float(it.y));
  }
  __syncthreads();
  int x = kcnt[t];
  int lane = t & 63, wid = t >> 6;
  int incl = x;
#pragma unroll
  for (int d = 1; d < 64; d <<= 1) {
    int tt = __shfl_up(incl, d, 64);
    if (lane >= d) incl += tt;
  }
  if (lane == 63) ws[wid] = incl;
  __syncthreads();
  int woff = 0;
  for (int k = 0; k < wid; ++k) woff += ws[k];
  int excl = woff + incl - x;
  kbase[t] = s + excl;
  float sum = fmaxf(ksum[t], 1e-6f);
  if (b < NB_E) {
    int kglob = (b << 8) | t;
    if (kglob < NEDGES) {
      off[kglob] = s + excl;
      dein[kglob] = 1.0f / sum;
    }
  } else {
    int kglob = ((b - NB_E) << 8) | t;
    if (kglob < NNODES) {
      off[NEDGES + kglob] = s + excl;
      dvis[kglob] = rsqrtf(sum);
    }
  }
  if (b == NB - 1 && t == 0) off[NKEYS] = s + cntb;
  __syncthreads();
  kcnt[t] = 0;
  __syncthreads();
  for (int j = t; j < cntb; j += 256) {
    int2 it = items[j];
    int k = it.x >> 18;
    int pos = kbase[k] + atomicAdd(&kcnt[k], 1);
    pair[pos] = make_int2(it.x & 0x3FFFF, it.y);
  }
}

// ===========================================================================
// scalex_h: Xh (fp16 row-major) = dvis * X0. One thread per float4 (4 elems).
// ===========================================================================
__global__ __launch_bounds__(256) void scalex_h_kernel(
    const float* __restrict__ X, const float* __restrict__ dvis,
    uint2* __restrict__ Yh) {
  int i = blockIdx.x * 256 + threadIdx.x;
  if (i >= NNODES * 32) return;
  float s = dvis[i >> 5];
  float4 v = reinterpret_cast<const float4*>(X)[i];
  __half2 a = __float22half2_rn(make_float2(s * v.x, s * v.y));
  __half2 b = __float22half2_rn(make_float2(s * v.z, s * v.w));
  uint2 o;
  o.x = *reinterpret_cast<unsigned*>(&a);
  o.y = *reinterpret_cast<unsigned*>(&b);
  Yh[i] = o;
}

// ===========================================================================
// gather v7 (fp16): ONE SEGMENT PER 16-LANE GROUP (4 segments/wave).
// Group's 16 lanes read the full 256 B fp16 row as uint4; 2-deep unroll
// keeps 2 rows/group (8/wave) in flight. fp32 accumulate; NO cross-group
// shuffles; all 16 lanes write the output row directly.
// ===========================================================================
__global__ __launch_bounds__(256) void gather_hh_kernel(
    const uint4* __restrict__ src, uint4* __restrict__ dst,
    const int* __restrict__ off, const int2* __restrict__ pair,
    const float* __restrict__ seg_scale, int nseg) {
  int e = blockIdx.x * 16 + (threadIdx.x >> 4);
  if (e >= nseg) return;
  int li = threadIdx.x & 15;
  int s = off[e], t = off[e + 1];
  float acc[8] = {0.f, 0.f, 0.f, 0.f, 0.f, 0.f, 0.f, 0.f};
  int j = s;
  for (; j + 1 < t; j += 2) {
    int2 p0 = pair[j], p1 = pair[j + 1];
    float w0 = __int_as_float(p0.y), w1 = __int_as_float(p1.y);
    uint4 u0 = src[(size_t)p0.x * 16 + li];
    uint4 u1 = src[(size_t)p1.x * 16 + li];
    float2 f0 = __half22float2(*reinterpret_cast<__half2*>(&u0.x));
    float2 f1 = __half22float2(*reinterpret_cast<__half2*>(&u0.y));
    float2 f2 = __half22float2(*reinterpret_cast<__half2*>(&u0.z));
    float2 f3 = __half22float2(*reinterpret_cast<__half2*>(&u0.w));
    acc[0] = fmaf(w0, f0.x, acc[0]); acc[1] = fmaf(w0, f0.y, acc[1]);
    acc[2] = fmaf(w0, f1.x, acc[2]); acc[3] = fmaf(w0, f1.y, acc[3]);
    acc[4] = fmaf(w0, f2.x, acc[4]); acc[5] = fmaf(w0, f2.y, acc[5]);
    acc[6] = fmaf(w0, f3.x, acc[6]); acc[7] = fmaf(w0, f3.y, acc[7]);
    float2 g0 = __half22float2(*reinterpret_cast<__half2*>(&u1.x));
    float2 g1 = __half22float2(*reinterpret_cast<__half2*>(&u1.y));
    float2 g2 = __half22float2(*reinterpret_cast<__half2*>(&u1.z));
    float2 g3 = __half22float2(*reinterpret_cast<__half2*>(&u1.w));
    acc[0] = fmaf(w1, g0.x, acc[0]); acc[1] = fmaf(w1, g0.y, acc[1]);
    acc[2] = fmaf(w1, g1.x, acc[2]); acc[3] = fmaf(w1, g1.y, acc[3]);
    acc[4] = fmaf(w1, g2.x, acc[4]); acc[5] = fmaf(w1, g2.y, acc[5]);
    acc[6] = fmaf(w1, g3.x, acc[6]); acc[7] = fmaf(w1, g3.y, acc[7]);
  }
  if (j < t) {
    int2 p0 = pair[j];
    float w0 = __int_as_float(p0.y);
    uint4 u0 = src[(size_t)p0.x * 16 + li];
    float2 f0 = __half22float2(*reinterpret_cast<__half2*>(&u0.x));
    float2 f1 = __half22float2(*reinterpret_cast<__half2*>(&u0.y));
    float2 f2 = __half22float2(*reinterpret_cast<__half2*>(&u0.z));
    float2 f3 = __half22float2(*reinterpret_cast<__half2*>(&u0.w));
    acc[0] = fmaf(w0, f0.x, acc[0]); acc[1] = fmaf(w0, f0.y, acc[1]);
    acc[2] = fmaf(w0, f1.x, acc[2]); acc[3] = fmaf(w0, f1.y, acc[3]);
    acc[4] = fmaf(w0, f2.x, acc[4]); acc[5] = fmaf(w0, f2.y, acc[5]);
    acc[6] = fmaf(w0, f3.x, acc[6]); acc[7] = fmaf(w0, f3.y, acc[7]);
  }
  float sc = seg_scale ? seg_scale[e] : 1.0f;
  __half2 h0 = __float22half2_rn(make_float2(sc * acc[0], sc * acc[1]));
  __half2 h1 = __float22half2_rn(make_float2(sc * acc[2], sc * acc[3]));
  __half2 h2 = __float22half2_rn(make_float2(sc * acc[4], sc * acc[5]));
  __half2 h3 = __float22half2_rn(make_float2(sc * acc[6], sc * acc[7]));
  uint4 o;
  o.x = *reinterpret_cast<unsigned*>(&h0);
  o.y = *reinterpret_cast<unsigned*>(&h1);
  o.z = *reinterpret_cast<unsigned*>(&h2);
  o.w = *reinterpret_cast<unsigned*>(&h3);
  dst[(size_t)e * 16 + li] = o;
}

// ===========================================================================
// GEMM (fp16 X rows): acc = Pnh[n,:] @ W^T[:, j0:j0+64]
// Pnh already carries the propagate dvis scale (node-gather epilogue).
// mode 0: acc -> fp32 d_out | mode 1: dvis*relu(acc) -> fp16 Xh (layer2 src)
// ===========================================================================
__device__ __forceinline__ void cvt8(uint4 u, float* f) {
  float2 a = __half22float2(*reinterpret_cast<__half2*>(&u.x));
  float2 b = __half22float2(*reinterpret_cast<__half2*>(&u.y));
  float2 c = __half22float2(*reinterpret_cast<__half2*>(&u.z));
  float2 d = __half22float2(*reinterpret_cast<__half2*>(&u.w));
  f[0] = a.x; f[1] = a.y; f[2] = b.x; f[3] = b.y;
  f[4] = c.x; f[5] = c.y; f[6] = d.x; f[7] = d.y;
}

__global__ __launch_bounds__(256) void gemm_h_kernel(
    const uint4* __restrict__ Pnh, const float* __restrict__ dvis,
    const float* __restrict__ W, void* __restrict__ out_v, int mode) {
  __shared__ float WT[128 * 64];  // 32 KB
  int t = threadIdx.x;
  int jb = blockIdx.x & 1;
  int rb = blockIdx.x >> 1;
  int j0 = jb << 6;
  {
    int K = t & 31;
    int Jb = t >> 5;
#pragma unroll
    for (int p = 0; p < 2; ++p) {
      int J = Jb + (p << 3);
      const float* Wb = W + (size_t)(j0 + 4 * J) * 128 + 4 * K;
      float4 g0 = *reinterpret_cast<const float4*>(Wb);
      float4 g1 = *reinterpret_cast<const float4*>(Wb + 128);
      float4 g2 = *reinterpret_cast<const float4*>(Wb + 256);
      float4 g3 = *reinterpret_cast<const float4*>(Wb + 384);
      const float* g0p = reinterpret_cast<const float*>(&g0);
      const float* g1p = reinterpret_cast<const float*>(&g1);
      const float* g2p = reinterpret_cast<const float*>(&g2);
      const float* g3p = reinterpret_cast<const float*>(&g3);
#pragma unroll
      for (int q = 0; q < 4; ++q) {
        int k = 4 * K + q;
        float4 hq = make_float4(g0p[q], g1p[q], g2p[q], g3p[q]);
        int slot = (J + k) & 15;
        *reinterpret_cast<float4*>(&WT[k * 64 + 4 * slot]) = hq;
      }
    }
  }
  __syncthreads();
  int u = t & 15;
  int rg = t >> 4;
  int rbase = rb * 64 + rg * 4;
  const float4* WT4 = reinterpret_cast<const float4*>(WT);
  float4 acc0 = make_float4(0.f, 0.f, 0.f, 0.f);
  float4 acc1 = acc0, acc2 = acc0, acc3 = acc0;
  int rr0 = rbase + 0; if (rr0 >= NNODES) rr0 = NNODES - 1;
  int rr1 = rbase + 1; if (rr1 >= NNODES) rr1 = NNODES - 1;
  int rr2 = rbase + 2; if (rr2 >= NNODES) rr2 = NNODES - 1;
  int rr3 = rbase + 3; if (rr3 >= NNODES) rr3 = NNODES - 1;
  const uint4* X0 = Pnh + (size_t)rr0 * 16;
  const uint4* X1 = Pnh + (size_t)rr1 * 16;
  const uint4* X2 = Pnh + (size_t)rr2 * 16;
  const uint4* X3 = Pnh + (size_t)rr3 * 16;
#pragma unroll 4
  for (int kk = 0; kk < 16; ++kk) {
    float x0f[8], x1f[8], x2f[8], x3f[8];
    cvt8(X0[kk], x0f);
    cvt8(X1[kk], x1f);
    cvt8(X2[kk], x2f);
    cvt8(X3[kk], x3f);
#pragma unroll
    for (int q = 0; q < 8; ++q) {
      int k = kk * 8 + q;
      float4 w4 = WT4[k * 16 + ((u + k) & 15)];
      acc0.x = fmaf(x0f[q], w4.x, acc0.x); acc0.y = fmaf(x0f[q], w4.y, acc0.y);
      acc0.z = fmaf(x0f[q], w4.z, acc0.z); acc0.w = fmaf(x0f[q], w4.w, acc0.w);
      acc1.x = fmaf(x1f[q], w4.x, acc1.x); acc1.y = fmaf(x1f[q], w4.y, acc1.y);
      acc1.z = fmaf(x1f[q], w4.z, acc1.z); acc1.w = fmaf(x1f[q], w4.w, acc1.w);
      acc2.x = fmaf(x2f[q], w4.x, acc2.x); acc2.y = fmaf(x2f[q], w4.y, acc2.y);
      acc2.z = fmaf(x2f[q], w4.z, acc2.z); acc2.w = fmaf(x2f[q], w4.w, acc2.w);
      acc3.x = fmaf(x3f[q], w4.x, acc3.x); acc3.y = fmaf(x3f[q], w4.y, acc3.y);
      acc3.z = fmaf(x3f[q], w4.z, acc3.z); acc3.w = fmaf(x3f[q], w4.w, acc3.w);
    }
  }
#pragma unroll
  for (int m = 0; m < 4; ++m) {
    int r = rbase + m;
    if (r >= NNODES) break;
    float4 a = (m == 0) ? acc0 : (m == 1) ? acc1 : (m == 2) ? acc2 : acc3;
    if (mode == 1) {
      float s = dvis[r];
      float4 o = make_float4(fmaxf(a.x, 0.f) * s, fmaxf(a.y, 0.f) * s,
                             fmaxf(a.z, 0.f) * s, fmaxf(a.w, 0.f) * s);
      __half2 ha = __float22half2_rn(make_float2(o.x, o.y));
      __half2 hb = __float22half2_rn(make_float2(o.z, o.w));
      uint2 ou;
      ou.x = *reinterpret_cast<unsigned*>(&ha);
      ou.y = *reinterpret_cast<unsigned*>(&hb);
      reinterpret_cast<uint2*>(out_v)[(size_t)r * 32 + (j0 >> 2) + u] = ou;
    } else {
      *reinterpret_cast<float4*>(
          &reinterpret_cast<float*>(out_v)[(size_t)r * 128 + j0 + 4 * u]) = a;
    }
  }
}

// ===========================================================================
// Fallback (atomic-scatter, row-major fp32) kernels — unused if ws suffices
// ===========================================================================
__global__ __launch_bounds__(256) void deg_fb_kernel(
    const int* __restrict__ rows, const int* __restrict__ cols,
    const float* __restrict__ vals, float* __restrict__ dv,
    float* __restrict__ de, int nnz) {
  int i = blockIdx.x * 256 + threadIdx.x;
  if (i >= nnz) return;
  float v = vals[i];
  unsafeAtomicAdd(&dv[rows[i]], v);
  unsafeAtomicAdd(&de[cols[i]], v);
}

__global__ __launch_bounds__(256) void inv_kernel(float* __restrict__ dv,
                                                  float* __restrict__ de) {
  int i = blockIdx.x * 256 + threadIdx.x;
  if (i < NNODES) {
    dv[i] = 1.0f / sqrtf(fmaxf(dv[i], 1e-6f));
  } else if (i < NNODES + NEDGES) {
    int j = i - NNODES;
    de[j] = 1.0f / fmaxf(de[j], 1e-6f);
  }
}

__global__ __launch_bounds__(256) void scatter_edge_kernel(
    const float* __restrict__ X, float* __restrict__ Ye,
    const int* __restrict__ rows, const int* __restrict__ cols,
    const float* __restrict__ vals, const float* __restrict__ dvis, int nnz) {
  int g = (blockIdx.x * 256 + threadIdx.x) >> 5;
  int lane = threadIdx.x & 31;
  if (g >= nnz) return;
  int r = rows[g], c = cols[g];
  float s = vals[g] * dvis[r];
  float4 x = reinterpret_cast<const float4*>(X)[(size_t)r * 32 + lane];
  float* dst = Ye + (size_t)c * HID + lane * 4;
  unsafeAtomicAdd(dst + 0, s * x.x);
  unsafeAtomicAdd(dst + 1, s * x.y);
  unsafeAtomicAdd(dst + 2, s * x.z);
  unsafeAtomicAdd(dst + 3, s * x.w);
}

__global__ __launch_bounds__(256) void scatter_node_kernel(
    const float* __restrict__ Ye, float* __restrict__ Yn,
    const int* __restrict__ rows, const int* __restrict__ cols,
    const float* __restrict__ vals, const float* __restrict__ dein, int nnz) {
  int g = (blockIdx.x * 256 + threadIdx.x) >> 5;
  int lane = threadIdx.x & 31;
  if (g >= nnz) return;
  int r = rows[g], c = cols[g];
  float s = vals[g] * dein[c];
  float4 y = reinterpret_cast<const float4*>(Ye)[(size_t)c * 32 + lane];
  float* dst = Yn + (size_t)r * HID + lane * 4;
  unsafeAtomicAdd(dst + 0, s * y.x);
  unsafeAtomicAdd(dst + 1, s * y.y);
  unsafeAtomicAdd(dst + 2, s * y.z);
  unsafeAtomicAdd(dst + 3, s * y.w);
}

// row-major fp32 GEMM for fallback. mode 2: relu(s*acc), mode 0: s*acc
__global__ __launch_bounds__(256) void gemm_rm_kernel(
    const float* __restrict__ Pn, const float* __restrict__ dvis,
    const float* __restrict__ W, float* __restrict__ out, int mode) {
  __shared__ float WT[128 * 64];
  int t = threadIdx.x;
  int jb = blockIdx.x & 1;
  int rb = blockIdx.x >> 1;
  int j0 = jb << 6;
  {
    int K = t & 31;
    int Jb = t >> 5;
#pragma unroll
    for (int p = 0; p < 2; ++p) {
      int J = Jb + (p << 3);
      const float* Wb = W + (size_t)(j0 + 4 * J) * 128 + 4 * K;
      float4 g0 = *reinterpret_cast<const float4*>(Wb);
      float4 g1 = *reinterpret_cast<const float4*>(Wb + 128);
      float4 g2 = *reinterpret_cast<const float4*>(Wb + 256);
      float4 g3 = *reinterpret_cast<const float4*>(Wb + 384);
      const float* g0p = reinterpret_cast<const float*>(&g0);
      const float* g1p = reinterpret_cast<const float*>(&g1);
      const float* g2p = reinterpret_cast<const float*>(&g2);
      const float* g3p = reinterpret_cast<const float*>(&g3);
#pragma unroll
      for (int q = 0; q < 4; ++q) {
        int k = 4 * K + q;
        float4 hq = make_float4(g0p[q], g1p[q], g2p[q], g3p[q]);
        int slot = (J + k) & 15;
        *reinterpret_cast<float4*>(&WT[k * 64 + 4 * slot]) = hq;
      }
    }
  }
  __syncthreads();
  int u = t & 15;
  int rg = t >> 4;
  int rbase = rb * 64 + rg * 4;
  const float4* WT4 = reinterpret_cast<const float4*>(WT);
  float4 acc0 = make_float4(0.f, 0.f, 0.f, 0.f);
  float4 acc1 = acc0, acc2 = acc0, acc3 = acc0;
  int rr0 = rbase + 0; if (rr0 >= NNODES) rr0 = NNODES - 1;
  int rr1 = rbase + 1; if (rr1 >= NNODES) rr1 = NNODES - 1;
  int rr2 = rbase + 2; if (rr2 >= NNODES) rr2 = NNODES - 1;
  int rr3 = rbase + 3; if (rr3 >= NNODES) rr3 = NNODES - 1;
  const float4* X0 = reinterpret_cast<const float4*>(Pn + (size_t)rr0 * 128);
  const float4* X1 = reinterpret_cast<const float4*>(Pn + (size_t)rr1 * 128);
  const float4* X2 = reinterpret_cast<const float4*>(Pn + (size_t)rr2 * 128);
  const float4* X3 = reinterpret_cast<const float4*>(Pn + (size_t)rr3 * 128);
#pragma unroll 4
  for (int kk = 0; kk < 32; ++kk) {
    float4 x0 = X0[kk], x1 = X1[kk], x2 = X2[kk], x3 = X3[kk];
    const float* x0p = reinterpret_cast<const float*>(&x0);
    const float* x1p = reinterpret_cast<const float*>(&x1);
    const float* x2p = reinterpret_cast<const float*>(&x2);
    const float* x3p = reinterpret_cast<const float*>(&x3);
#pragma unroll
    for (int q = 0; q < 4; ++q) {
      int k = 4 * kk + q;
      float4 w4 = WT4[k * 16 + ((u + k) & 15)];
      acc0.x = fmaf(x0p[q], w4.x, acc0.x); acc0.y = fmaf(x0p[q], w4.y, acc0.y);
      acc0.z = fmaf(x0p[q], w4.z, acc0.z); acc0.w = fmaf(x0p[q], w4.w, acc0.w);
      acc1.x = fmaf(x1p[q], w4.x, acc1.x); acc1.y = fmaf(x1p[q], w4.y, acc1.y);
      acc1.z = fmaf(x1p[q], w4.z, acc1.z); acc1.w = fmaf(x1p[q], w4.w, acc1.w);
      acc2.x = fmaf(x2p[q], w4.x, acc2.x); acc2.y = fmaf(x2p[q], w4.y, acc2.y);
      acc2.z = fmaf(x2p[q], w4.z, acc2.z); acc2.w = fmaf(x2p[q], w4.w, acc2.w);
      acc3.x = fmaf(x3p[q], w4.x, acc3.x); acc3.y = fmaf(x3p[q], w4.y, acc3.y);
      acc3.z = fmaf(x3p[q], w4.z, acc3.z); acc3.w = fmaf(x3p[q], w4.w, acc3.w);
    }
  }
#pragma unroll
  for (int m = 0; m < 4; ++m) {
    int r = rbase + m;
    if (r >= NNODES) break;
    float4 a = (m == 0) ? acc0 : (m == 1) ? acc1 : (m == 2) ? acc2 : acc3;
    float s = dvis[r];
    float4 o = make_float4(s * a.x, s * a.y, s * a.z, s * a.w);
    if (mode == 2) {
      o.x = fmaxf(o.x, 0.f); o.y = fmaxf(o.y, 0.f);
      o.z = fmaxf(o.z, 0.f); o.w = fmaxf(o.w, 0.f);
    }
    *reinterpret_cast<float4*>(&out[(size_t)r * 128 + j0 + 4 * u]) = o;
  }
}

// ===========================================================================
extern "C" void kernel_launch(void* const* d_in, const int* in_sizes, int n_in,
                              void* d_out, int out_size, void* d_ws,
                              size_t ws_size, hipStream_t stream) {
  const int* rows = (const int*)d_in[0];
  const int* cols = (const int*)d_in[1];
  const float* vals = (const float*)d_in[2];
  const float* X0 = (const float*)d_in[3];
  const float* W0 = (const float*)d_in[4];
  const float* W1 = (const float*)d_in[5];
  const int nnz = in_sizes[0];
  float* out = (float*)d_out;

  const int gemm_blocks = ((NNODES + 63) / 64) * 2;

  // fp16 CSR-path workspace (4 B elems):
  // pair[2*nnz int2] | Yeh[E*16 uint4] (bkt_items staging alias) |
  // Xh[N*16 uint4] | Pnh[N*16 uint4] | dvis[N] | dein[E] | off[NKEYS+1] |
  // bucket_cur[NB] | bucket_base[NB+1]
  size_t bkt_cap = (size_t)NB_E * CAP_E + (size_t)NB_N * CAP_N;  // entries
  size_t ye_elems = (size_t)NEDGES * 64;
  size_t xh_elems = (size_t)NNODES * 64;
  size_t elems = 4 * (size_t)nnz + ye_elems + 2 * xh_elems + NNODES + NEDGES +
                 (NKEYS + 1) + NB + (NB + 1);
  size_t need = elems * 4;
  bool bkt_fits = 2 * bkt_cap <= ye_elems;  // staging aliases Yeh

  if (ws_size >= need && bkt_fits && (size_t)2 * nnz <= bkt_cap) {
    int2* pair = (int2*)d_ws;
    uint4* Yeh = (uint4*)(pair + 2 * (size_t)nnz);
    int2* bkt_items = (int2*)Yeh;  // preprocessing alias
    uint4* Xh = Yeh + (size_t)NEDGES * 16;
    uint4* Pnh = Xh + (size_t)NNODES * 16;
    float* dvis = (float*)(Pnh + (size_t)NNODES * 16);
    float* dein = dvis + NNODES;
    int* off = (int*)(dein + NEDGES);
    int* bucket_cur = off + NKEYS + 1;
    int* bucket_base = bucket_cur + NB;

    hipMemsetAsync(bucket_cur, 0, NB * sizeof(int), stream);
    partition_kernel<<<(nnz + PART_CHUNK - 1) / PART_CHUNK, 256, 0, stream>>>(
        rows, cols, vals, bucket_cur, bkt_items, nnz);
    bucket_scan_kernel<<<1, 1024, 0, stream>>>(bucket_cur, bucket_base);
    place_kernel<<<NB, 256, 0, stream>>>(bucket_base, bucket_cur, bkt_items,
                                         off, pair, dein, dvis);
    scalex_h_kernel<<<(NNODES * 32 + 255) / 256, 256, 0, stream>>>(
        X0, dvis, (uint2*)Xh);

    const int eg_blocks = (NEDGES + 15) / 16;
    const int ng_blocks = (NNODES + 15) / 16;

    // layer 1
    gather_hh_kernel<<<eg_blocks, 256, 0, stream>>>(Xh, Yeh, off, pair, dein,
                                                    NEDGES);
    gather_hh_kernel<<<ng_blocks, 256, 0, stream>>>(Yeh, Pnh, off + NEDGES,
                                                    pair, dvis, NNODES);
    gemm_h_kernel<<<gemm_blocks, 256, 0, stream>>>(Pnh, dvis, W0, Xh, 1);

    // layer 2
    gather_hh_kernel<<<eg_blocks, 256, 0, stream>>>(Xh, Yeh, off, pair, dein,
                                                    NEDGES);
    gather_hh_kernel<<<ng_blocks, 256, 0, stream>>>(Yeh, Pnh, off + NEDGES,
                                                    pair, dvis, NNODES);
    gemm_h_kernel<<<gemm_blocks, 256, 0, stream>>>(Pnh, dvis, W1, out, 0);
    return;
  }

  // ---------- fallback: fp32 atomic-scatter path (row-major) ----------
  float* dv = (float*)d_ws;
  float* de = dv + NNODES;
  float* Ye = de + NEDGES;
  float* Pn = Ye + (size_t)NEDGES * HID;
  const int scat_blocks = (nnz + 7) / 8;

  hipMemsetAsync(dv, 0, (size_t)(NNODES + NEDGES) * sizeof(float), stream);
  deg_fb_kernel<<<(nnz + 255) / 256, 256, 0, stream>>>(rows, cols, vals, dv,
                                                       de, nnz);
  inv_kernel<<<(NNODES + NEDGES + 255) / 256, 256, 0, stream>>>(dv, de);

  hipMemsetAsync(Ye, 0, (size_t)NEDGES * HID * sizeof(float), stream);
  scatter_edge_kernel<<<scat_blocks, 256, 0, stream>>>(X0, Ye, rows, cols,
                                                       vals, dv, nnz);
  hipMemsetAsync(Pn, 0, (size_t)NNODES * HID * sizeof(float), stream);
  scatter_node_kernel<<<scat_blocks, 256, 0, stream>>>(Ye, Pn, rows, cols,
                                                       vals, de, nnz);
  gemm_rm_kernel<<<gemm_blocks, 256, 0, stream>>>(Pn, dv, W0, out, 2);

  hipMemsetAsync(Ye, 0, (size_t)NEDGES * HID * sizeof(float), stream);
  scatter_edge_kernel<<<scat_blocks, 256, 0, stream>>>(out, Ye, rows, cols,
                                                       vals, dv, nnz);
  hipMemsetAsync(Pn, 0, (size_t)NNODES * HID * sizeof(float), stream);
  scatter_node_kernel<<<scat_blocks, 256, 0, stream>>>(Ye, Pn, rows, cols,
                                                       vals, de, nnz);
  gemm_rm_kernel<<<gemm_blocks, 256, 0, stream>>>(Pn, dv, W1, out, 0);
}

// Round 16
// 289.420 us; speedup vs baseline: 1.1082x; 1.0220x over previous
//
#include <hip/hip_runtime.h>
#include <hip/hip_fp16.h>
#include <math.h>

#define NNODES 50000
#define NEDGES 100000
#define HID 128
#define NKEYS (NEDGES + NNODES)  // edge keys then node keys

// bucket decomposition: 256 keys per bucket
#define NB_E ((NEDGES + 255) >> 8)  // 391
#define NB_N ((NNODES + 255) >> 8)  // 196
#define NB (NB_E + NB_N)            // 587
#define CAP_E 3072                  // staging capacity per edge bucket
#define CAP_N 6144                  // staging capacity per node bucket
#define PART_CHUNK 2048
#define PART_THREADS 512

__device__ __forceinline__ int region_start(int b) {
  return (b < NB_E) ? b * CAP_E : NB_E * CAP_E + (b - NB_E) * CAP_N;
}

// ===========================================================================
// partition: per-block LDS hist -> reserve in fixed-capacity bucket regions
// item.x = (key_low8 << 18) | neighbor(17b), item.y = val bits
// bucket_cur (zero-init) accumulates per-bucket counts.
// 512 threads/block: extra waves hide scattered-write latency.
// ===========================================================================
__global__ __launch_bounds__(PART_THREADS) void partition_kernel(
    const int* __restrict__ rows, const int* __restrict__ cols,
    const float* __restrict__ vals, int* __restrict__ bucket_cur,
    int2* __restrict__ bkt_items, int nnz) {
  __shared__ int cnt[NB];
  __shared__ int wbase[NB];
  for (int k = threadIdx.x; k < NB; k += PART_THREADS) cnt[k] = 0;
  __syncthreads();
  int start = blockIdx.x * PART_CHUNK;
  int end = start + PART_CHUNK;
  if (end > nnz) end = nnz;
  for (int i = start + threadIdx.x; i < end; i += PART_THREADS) {
    atomicAdd(&cnt[cols[i] >> 8], 1);
    atomicAdd(&cnt[NB_E + (rows[i] >> 8)], 1);
  }
  __syncthreads();
  for (int k = threadIdx.x; k < NB; k += PART_THREADS) {
    int c = cnt[k];
    wbase[k] = c ? region_start(k) + atomicAdd(&bucket_cur[k], c) : 0;
    cnt[k] = 0;
  }
  __syncthreads();
  for (int i = start + threadIdx.x; i < end; i += PART_THREADS) {
    int c = cols[i], r = rows[i];
    int v = __float_as_int(vals[i]);
    int be = c >> 8;
    int p = wbase[be] + atomicAdd(&cnt[be], 1);
    bkt_items[p] = make_int2(((c & 255) << 18) | r, v);
    int bn = NB_E + (r >> 8);
    int q = wbase[bn] + atomicAdd(&cnt[bn], 1);
    bkt_items[q] = make_int2(((r & 255) << 18) | c, v);
  }
}

// exclusive scan of NB bucket counts -> dense bases. one block.
__global__ __launch_bounds__(1024) void bucket_scan_kernel(
    const int* __restrict__ bucket_cur, int* __restrict__ bucket_base) {
  int t = threadIdx.x;
  int lane = t & 63, wid = t >> 6;
  int x = (t < NB) ? bucket_cur[t] : 0;
  int incl = x;
#pragma unroll
  for (int d = 1; d < 64; d <<= 1) {
    int tt = __shfl_up(incl, d, 64);
    if (lane >= d) incl += tt;
  }
  __shared__ int ws[16];
  if (lane == 63) ws[wid] = incl;
  __syncthreads();
  int woff = 0;
  for (int k = 0; k < wid; ++k) woff += ws[k];
  int excl = woff + incl - x;
  if (t < NB) bucket_base[t] = excl;
  if (t == NB - 1) bucket_base[NB] = excl + x;  // == 2*nnz
}

// ===========================================================================
// place v2: one block per bucket; caches staged region in LDS (<= CAP_N
// items = 48 KB), per-key LDS hist+scan (+ fused degree sums); writes dense
// off[], pair[], dein/dvis.
// ===========================================================================
__global__ __launch_bounds__(256) void place_kernel(
    const int* __restrict__ bucket_base, const int* __restrict__ bucket_cur,
    const int2* __restrict__ bkt_items, int* __restrict__ off,
    int2* __restrict__ pair, float* __restrict__ dein,
    float* __restrict__ dvis) {
  __shared__ int2 items[CAP_N];  // 48 KB
  __shared__ int kcnt[256];
  __shared__ float ksum[256];
  __shared__ int kbase[256];
  __shared__ int ws[4];
  int b = blockIdx.x;
  int rs = region_start(b);
  int cntb = bucket_cur[b];
  int s = bucket_base[b];
  int t = threadIdx.x;
  kcnt[t] = 0;
  ksum[t] = 0.f;
  __syncthreads();
  for (int j = t; j < cntb; j += 256) {
    int2 it = bkt_items[rs + j];
    items[j] = it;
    int k = it.x >> 18;
    atomicAdd(&kcnt[k], 1);
    atomicAdd(&ksum[k], __int_as_float(it.y));
  }
  __syncthreads();
  int x = kcnt[t];
  int lane = t & 63, wid = t >> 6;
  int incl = x;
#pragma unroll
  for (int d = 1; d < 64; d <<= 1) {
    int tt = __shfl_up(incl, d, 64);
    if (lane >= d) incl += tt;
  }
  if (lane == 63) ws[wid] = incl;
  __syncthreads();
  int woff = 0;
  for (int k = 0; k < wid; ++k) woff += ws[k];
  int excl = woff + incl - x;
  kbase[t] = s + excl;
  float sum = fmaxf(ksum[t], 1e-6f);
  if (b < NB_E) {
    int kglob = (b << 8) | t;
    if (kglob < NEDGES) {
      off[kglob] = s + excl;
      dein[kglob] = 1.0f / sum;
    }
  } else {
    int kglob = ((b - NB_E) << 8) | t;
    if (kglob < NNODES) {
      off[NEDGES + kglob] = s + excl;
      dvis[kglob] = rsqrtf(sum);
    }
  }
  if (b == NB - 1 && t == 0) off[NKEYS] = s + cntb;
  __syncthreads();
  kcnt[t] = 0;
  __syncthreads();
  for (int j = t; j < cntb; j += 256) {
    int2 it = items[j];
    int k = it.x >> 18;
    int pos = kbase[k] + atomicAdd(&kcnt[k], 1);
    pair[pos] = make_int2(it.x & 0x3FFFF, it.y);
  }
}

// ===========================================================================
// scalex_h: Xh (fp16 row-major) = dvis * X0. One thread per float4 (4 elems).
// ===========================================================================
__global__ __launch_bounds__(256) void scalex_h_kernel(
    const float* __restrict__ X, const float* __restrict__ dvis,
    uint2* __restrict__ Yh) {
  int i = blockIdx.x * 256 + threadIdx.x;
  if (i >= NNODES * 32) return;
  float s = dvis[i >> 5];
  float4 v = reinterpret_cast<const float4*>(X)[i];
  __half2 a = __float22half2_rn(make_float2(s * v.x, s * v.y));
  __half2 b = __float22half2_rn(make_float2(s * v.z, s * v.w));
  uint2 o;
  o.x = *reinterpret_cast<unsigned*>(&a);
  o.y = *reinterpret_cast<unsigned*>(&b);
  Yh[i] = o;
}

// ===========================================================================
// gather v7 (fp16): ONE SEGMENT PER 16-LANE GROUP (4 segments/wave).
// Group's 16 lanes read the full 256 B fp16 row as uint4; 2-deep unroll
// keeps 2 rows/group (8/wave) in flight. fp32 accumulate; NO cross-group
// shuffles; all 16 lanes write the output row directly.
// ===========================================================================
__global__ __launch_bounds__(256) void gather_hh_kernel(
    const uint4* __restrict__ src, uint4* __restrict__ dst,
    const int* __restrict__ off, const int2* __restrict__ pair,
    const float* __restrict__ seg_scale, int nseg) {
  int e = blockIdx.x * 16 + (threadIdx.x >> 4);
  if (e >= nseg) return;
  int li = threadIdx.x & 15;
  int s = off[e], t = off[e + 1];
  float acc[8] = {0.f, 0.f, 0.f, 0.f, 0.f, 0.f, 0.f, 0.f};
  int j = s;
  for (; j + 1 < t; j += 2) {
    int2 p0 = pair[j], p1 = pair[j + 1];
    float w0 = __int_as_float(p0.y), w1 = __int_as_float(p1.y);
    uint4 u0 = src[(size_t)p0.x * 16 + li];
    uint4 u1 = src[(size_t)p1.x * 16 + li];
    float2 f0 = __half22float2(*reinterpret_cast<__half2*>(&u0.x));
    float2 f1 = __half22float2(*reinterpret_cast<__half2*>(&u0.y));
    float2 f2 = __half22float2(*reinterpret_cast<__half2*>(&u0.z));
    float2 f3 = __half22float2(*reinterpret_cast<__half2*>(&u0.w));
    acc[0] = fmaf(w0, f0.x, acc[0]); acc[1] = fmaf(w0, f0.y, acc[1]);
    acc[2] = fmaf(w0, f1.x, acc[2]); acc[3] = fmaf(w0, f1.y, acc[3]);
    acc[4] = fmaf(w0, f2.x, acc[4]); acc[5] = fmaf(w0, f2.y, acc[5]);
    acc[6] = fmaf(w0, f3.x, acc[6]); acc[7] = fmaf(w0, f3.y, acc[7]);
    float2 g0 = __half22float2(*reinterpret_cast<__half2*>(&u1.x));
    float2 g1 = __half22float2(*reinterpret_cast<__half2*>(&u1.y));
    float2 g2 = __half22float2(*reinterpret_cast<__half2*>(&u1.z));
    float2 g3 = __half22float2(*reinterpret_cast<__half2*>(&u1.w));
    acc[0] = fmaf(w1, g0.x, acc[0]); acc[1] = fmaf(w1, g0.y, acc[1]);
    acc[2] = fmaf(w1, g1.x, acc[2]); acc[3] = fmaf(w1, g1.y, acc[3]);
    acc[4] = fmaf(w1, g2.x, acc[4]); acc[5] = fmaf(w1, g2.y, acc[5]);
    acc[6] = fmaf(w1, g3.x, acc[6]); acc[7] = fmaf(w1, g3.y, acc[7]);
  }
  if (j < t) {
    int2 p0 = pair[j];
    float w0 = __int_as_float(p0.y);
    uint4 u0 = src[(size_t)p0.x * 16 + li];
    float2 f0 = __half22float2(*reinterpret_cast<__half2*>(&u0.x));
    float2 f1 = __half22float2(*reinterpret_cast<__half2*>(&u0.y));
    float2 f2 = __half22float2(*reinterpret_cast<__half2*>(&u0.z));
    float2 f3 = __half22float2(*reinterpret_cast<__half2*>(&u0.w));
    acc[0] = fmaf(w0, f0.x, acc[0]); acc[1] = fmaf(w0, f0.y, acc[1]);
    acc[2] = fmaf(w0, f1.x, acc[2]); acc[3] = fmaf(w0, f1.y, acc[3]);
    acc[4] = fmaf(w0, f2.x, acc[4]); acc[5] = fmaf(w0, f2.y, acc[5]);
    acc[6] = fmaf(w0, f3.x, acc[6]); acc[7] = fmaf(w0, f3.y, acc[7]);
  }
  float sc = seg_scale ? seg_scale[e] : 1.0f;
  __half2 h0 = __float22half2_rn(make_float2(sc * acc[0], sc * acc[1]));
  __half2 h1 = __float22half2_rn(make_float2(sc * acc[2], sc * acc[3]));
  __half2 h2 = __float22half2_rn(make_float2(sc * acc[4], sc * acc[5]));
  __half2 h3 = __float22half2_rn(make_float2(sc * acc[6], sc * acc[7]));
  uint4 o;
  o.x = *reinterpret_cast<unsigned*>(&h0);
  o.y = *reinterpret_cast<unsigned*>(&h1);
  o.z = *reinterpret_cast<unsigned*>(&h2);
  o.w = *reinterpret_cast<unsigned*>(&h3);
  dst[(size_t)e * 16 + li] = o;
}

// ===========================================================================
// GEMM (fp16 X rows): acc = Pnh[n,:] @ W^T[:, j0:j0+64]
// Pnh already carries the propagate dvis scale (node-gather epilogue).
// mode 0: acc -> fp32 d_out | mode 1: dvis*relu(acc) -> fp16 Xh (layer2 src)
// ===========================================================================
__device__ __forceinline__ void cvt8(uint4 u, float* f) {
  float2 a = __half22float2(*reinterpret_cast<__half2*>(&u.x));
  float2 b = __half22float2(*reinterpret_cast<__half2*>(&u.y));
  float2 c = __half22float2(*reinterpret_cast<__half2*>(&u.z));
  float2 d = __half22float2(*reinterpret_cast<__half2*>(&u.w));
  f[0] = a.x; f[1] = a.y; f[2] = b.x; f[3] = b.y;
  f[4] = c.x; f[5] = c.y; f[6] = d.x; f[7] = d.y;
}

__global__ __launch_bounds__(256) void gemm_h_kernel(
    const uint4* __restrict__ Pnh, const float* __restrict__ dvis,
    const float* __restrict__ W, void* __restrict__ out_v, int mode) {
  __shared__ float WT[128 * 64];  // 32 KB
  int t = threadIdx.x;
  int jb = blockIdx.x & 1;
  int rb = blockIdx.x >> 1;
  int j0 = jb << 6;
  {
    int K = t & 31;
    int Jb = t >> 5;
#pragma unroll
    for (int p = 0; p < 2; ++p) {
      int J = Jb + (p << 3);
      const float* Wb = W + (size_t)(j0 + 4 * J) * 128 + 4 * K;
      float4 g0 = *reinterpret_cast<const float4*>(Wb);
      float4 g1 = *reinterpret_cast<const float4*>(Wb + 128);
      float4 g2 = *reinterpret_cast<const float4*>(Wb + 256);
      float4 g3 = *reinterpret_cast<const float4*>(Wb + 384);
      const float* g0p = reinterpret_cast<const float*>(&g0);
      const float* g1p = reinterpret_cast<const float*>(&g1);
      const float* g2p = reinterpret_cast<const float*>(&g2);
      const float* g3p = reinterpret_cast<const float*>(&g3);
#pragma unroll
      for (int q = 0; q < 4; ++q) {
        int k = 4 * K + q;
        float4 hq = make_float4(g0p[q], g1p[q], g2p[q], g3p[q]);
        int slot = (J + k) & 15;
        *reinterpret_cast<float4*>(&WT[k * 64 + 4 * slot]) = hq;
      }
    }
  }
  __syncthreads();
  int u = t & 15;
  int rg = t >> 4;
  int rbase = rb * 64 + rg * 4;
  const float4* WT4 = reinterpret_cast<const float4*>(WT);
  float4 acc0 = make_float4(0.f, 0.f, 0.f, 0.f);
  float4 acc1 = acc0, acc2 = acc0, acc3 = acc0;
  int rr0 = rbase + 0; if (rr0 >= NNODES) rr0 = NNODES - 1;
  int rr1 = rbase + 1; if (rr1 >= NNODES) rr1 = NNODES - 1;
  int rr2 = rbase + 2; if (rr2 >= NNODES) rr2 = NNODES - 1;
  int rr3 = rbase + 3; if (rr3 >= NNODES) rr3 = NNODES - 1;
  const uint4* X0 = Pnh + (size_t)rr0 * 16;
  const uint4* X1 = Pnh + (size_t)rr1 * 16;
  const uint4* X2 = Pnh + (size_t)rr2 * 16;
  const uint4* X3 = Pnh + (size_t)rr3 * 16;
#pragma unroll 4
  for (int kk = 0; kk < 16; ++kk) {
    float x0f[8], x1f[8], x2f[8], x3f[8];
    cvt8(X0[kk], x0f);
    cvt8(X1[kk], x1f);
    cvt8(X2[kk], x2f);
    cvt8(X3[kk], x3f);
#pragma unroll
    for (int q = 0; q < 8; ++q) {
      int k = kk * 8 + q;
      float4 w4 = WT4[k * 16 + ((u + k) & 15)];
      acc0.x = fmaf(x0f[q], w4.x, acc0.x); acc0.y = fmaf(x0f[q], w4.y, acc0.y);
      acc0.z = fmaf(x0f[q], w4.z, acc0.z); acc0.w = fmaf(x0f[q], w4.w, acc0.w);
      acc1.x = fmaf(x1f[q], w4.x, acc1.x); acc1.y = fmaf(x1f[q], w4.y, acc1.y);
      acc1.z = fmaf(x1f[q], w4.z, acc1.z); acc1.w = fmaf(x1f[q], w4.w, acc1.w);
      acc2.x = fmaf(x2f[q], w4.x, acc2.x); acc2.y = fmaf(x2f[q], w4.y, acc2.y);
      acc2.z = fmaf(x2f[q], w4.z, acc2.z); acc2.w = fmaf(x2f[q], w4.w, acc2.w);
      acc3.x = fmaf(x3f[q], w4.x, acc3.x); acc3.y = fmaf(x3f[q], w4.y, acc3.y);
      acc3.z = fmaf(x3f[q], w4.z, acc3.z); acc3.w = fmaf(x3f[q], w4.w, acc3.w);
    }
  }
#pragma unroll
  for (int m = 0; m < 4; ++m) {
    int r = rbase + m;
    if (r >= NNODES) break;
    float4 a = (m == 0) ? acc0 : (m == 1) ? acc1 : (m == 2) ? acc2 : acc3;
    if (mode == 1) {
      float s = dvis[r];
      float4 o = make_float4(fmaxf(a.x, 0.f) * s, fmaxf(a.y, 0.f) * s,
                             fmaxf(a.z, 0.f) * s, fmaxf(a.w, 0.f) * s);
      __half2 ha = __float22half2_rn(make_float2(o.x, o.y));
      __half2 hb = __float22half2_rn(make_float2(o.z, o.w));
      uint2 ou;
      ou.x = *reinterpret_cast<unsigned*>(&ha);
      ou.y = *reinterpret_cast<unsigned*>(&hb);
      reinterpret_cast<uint2*>(out_v)[(size_t)r * 32 + (j0 >> 2) + u] = ou;
    } else {
      *reinterpret_cast<float4*>(
          &reinterpret_cast<float*>(out_v)[(size_t)r * 128 + j0 + 4 * u]) = a;
    }
  }
}

// ===========================================================================
// Fallback (atomic-scatter, row-major fp32) kernels — unused if ws suffices
// ===========================================================================
__global__ __launch_bounds__(256) void deg_fb_kernel(
    const int* __restrict__ rows, const int* __restrict__ cols,
    const float* __restrict__ vals, float* __restrict__ dv,
    float* __restrict__ de, int nnz) {
  int i = blockIdx.x * 256 + threadIdx.x;
  if (i >= nnz) return;
  float v = vals[i];
  unsafeAtomicAdd(&dv[rows[i]], v);
  unsafeAtomicAdd(&de[cols[i]], v);
}

__global__ __launch_bounds__(256) void inv_kernel(float* __restrict__ dv,
                                                  float* __restrict__ de) {
  int i = blockIdx.x * 256 + threadIdx.x;
  if (i < NNODES) {
    dv[i] = 1.0f / sqrtf(fmaxf(dv[i], 1e-6f));
  } else if (i < NNODES + NEDGES) {
    int j = i - NNODES;
    de[j] = 1.0f / fmaxf(de[j], 1e-6f);
  }
}

__global__ __launch_bounds__(256) void scatter_edge_kernel(
    const float* __restrict__ X, float* __restrict__ Ye,
    const int* __restrict__ rows, const int* __restrict__ cols,
    const float* __restrict__ vals, const float* __restrict__ dvis, int nnz) {
  int g = (blockIdx.x * 256 + threadIdx.x) >> 5;
  int lane = threadIdx.x & 31;
  if (g >= nnz) return;
  int r = rows[g], c = cols[g];
  float s = vals[g] * dvis[r];
  float4 x = reinterpret_cast<const float4*>(X)[(size_t)r * 32 + lane];
  float* dst = Ye + (size_t)c * HID + lane * 4;
  unsafeAtomicAdd(dst + 0, s * x.x);
  unsafeAtomicAdd(dst + 1, s * x.y);
  unsafeAtomicAdd(dst + 2, s * x.z);
  unsafeAtomicAdd(dst + 3, s * x.w);
}

__global__ __launch_bounds__(256) void scatter_node_kernel(
    const float* __restrict__ Ye, float* __restrict__ Yn,
    const int* __restrict__ rows, const int* __restrict__ cols,
    const float* __restrict__ vals, const float* __restrict__ dein, int nnz) {
  int g = (blockIdx.x * 256 + threadIdx.x) >> 5;
  int lane = threadIdx.x & 31;
  if (g >= nnz) return;
  int r = rows[g], c = cols[g];
  float s = vals[g] * dein[c];
  float4 y = reinterpret_cast<const float4*>(Ye)[(size_t)c * 32 + lane];
  float* dst = Yn + (size_t)r * HID + lane * 4;
  unsafeAtomicAdd(dst + 0, s * y.x);
  unsafeAtomicAdd(dst + 1, s * y.y);
  unsafeAtomicAdd(dst + 2, s * y.z);
  unsafeAtomicAdd(dst + 3, s * y.w);
}

// row-major fp32 GEMM for fallback. mode 2: relu(s*acc), mode 0: s*acc
__global__ __launch_bounds__(256) void gemm_rm_kernel(
    const float* __restrict__ Pn, const float* __restrict__ dvis,
    const float* __restrict__ W, float* __restrict__ out, int mode) {
  __shared__ float WT[128 * 64];
  int t = threadIdx.x;
  int jb = blockIdx.x & 1;
  int rb = blockIdx.x >> 1;
  int j0 = jb << 6;
  {
    int K = t & 31;
    int Jb = t >> 5;
#pragma unroll
    for (int p = 0; p < 2; ++p) {
      int J = Jb + (p << 3);
      const float* Wb = W + (size_t)(j0 + 4 * J) * 128 + 4 * K;
      float4 g0 = *reinterpret_cast<const float4*>(Wb);
      float4 g1 = *reinterpret_cast<const float4*>(Wb + 128);
      float4 g2 = *reinterpret_cast<const float4*>(Wb + 256);
      float4 g3 = *reinterpret_cast<const float4*>(Wb + 384);
      const float* g0p = reinterpret_cast<const float*>(&g0);
      const float* g1p = reinterpret_cast<const float*>(&g1);
      const float* g2p = reinterpret_cast<const float*>(&g2);
      const float* g3p = reinterpret_cast<const float*>(&g3);
#pragma unroll
      for (int q = 0; q < 4; ++q) {
        int k = 4 * K + q;
        float4 hq = make_float4(g0p[q], g1p[q], g2p[q], g3p[q]);
        int slot = (J + k) & 15;
        *reinterpret_cast<float4*>(&WT[k * 64 + 4 * slot]) = hq;
      }
    }
  }
  __syncthreads();
  int u = t & 15;
  int rg = t >> 4;
  int rbase = rb * 64 + rg * 4;
  const float4* WT4 = reinterpret_cast<const float4*>(WT);
  float4 acc0 = make_float4(0.f, 0.f, 0.f, 0.f);
  float4 acc1 = acc0, acc2 = acc0, acc3 = acc0;
  int rr0 = rbase + 0; if (rr0 >= NNODES) rr0 = NNODES - 1;
  int rr1 = rbase + 1; if (rr1 >= NNODES) rr1 = NNODES - 1;
  int rr2 = rbase + 2; if (rr2 >= NNODES) rr2 = NNODES - 1;
  int rr3 = rbase + 3; if (rr3 >= NNODES) rr3 = NNODES - 1;
  const float4* X0 = reinterpret_cast<const float4*>(Pn + (size_t)rr0 * 128);
  const float4* X1 = reinterpret_cast<const float4*>(Pn + (size_t)rr1 * 128);
  const float4* X2 = reinterpret_cast<const float4*>(Pn + (size_t)rr2 * 128);
  const float4* X3 = reinterpret_cast<const float4*>(Pn + (size_t)rr3 * 128);
#pragma unroll 4
  for (int kk = 0; kk < 32; ++kk) {
    float4 x0 = X0[kk], x1 = X1[kk], x2 = X2[kk], x3 = X3[kk];
    const float* x0p = reinterpret_cast<const float*>(&x0);
    const float* x1p = reinterpret_cast<const float*>(&x1);
    const float* x2p = reinterpret_cast<const float*>(&x2);
    const float* x3p = reinterpret_cast<const float*>(&x3);
#pragma unroll
    for (int q = 0; q < 4; ++q) {
      int k = 4 * kk + q;
      float4 w4 = WT4[k * 16 + ((u + k) & 15)];
      acc0.x = fmaf(x0p[q], w4.x, acc0.x); acc0.y = fmaf(x0p[q], w4.y, acc0.y);
      acc0.z = fmaf(x0p[q], w4.z, acc0.z); acc0.w = fmaf(x0p[q], w4.w, acc0.w);
      acc1.x = fmaf(x1p[q], w4.x, acc1.x); acc1.y = fmaf(x1p[q], w4.y, acc1.y);
      acc1.z = fmaf(x1p[q], w4.z, acc1.z); acc1.w = fmaf(x1p[q], w4.w, acc1.w);
      acc2.x = fmaf(x2p[q], w4.x, acc2.x); acc2.y = fmaf(x2p[q], w4.y, acc2.y);
      acc2.z = fmaf(x2p[q], w4.z, acc2.z); acc2.w = fmaf(x2p[q], w4.w, acc2.w);
      acc3.x = fmaf(x3p[q], w4.x, acc3.x); acc3.y = fmaf(x3p[q], w4.y, acc3.y);
      acc3.z = fmaf(x3p[q], w4.z, acc3.z); acc3.w = fmaf(x3p[q], w4.w, acc3.w);
    }
  }
#pragma unroll
  for (int m = 0; m < 4; ++m) {
    int r = rbase + m;
    if (r >= NNODES) break;
    float4 a = (m == 0) ? acc0 : (m == 1) ? acc1 : (m == 2) ? acc2 : acc3;
    float s = dvis[r];
    float4 o = make_float4(s * a.x, s * a.y, s * a.z, s * a.w);
    if (mode == 2) {
      o.x = fmaxf(o.x, 0.f); o.y = fmaxf(o.y, 0.f);
      o.z = fmaxf(o.z, 0.f); o.w = fmaxf(o.w, 0.f);
    }
    *reinterpret_cast<float4*>(&out[(size_t)r * 128 + j0 + 4 * u]) = o;
  }
}

// ===========================================================================
extern "C" void kernel_launch(void* const* d_in, const int* in_sizes, int n_in,
                              void* d_out, int out_size, void* d_ws,
                              size_t ws_size, hipStream_t stream) {
  const int* rows = (const int*)d_in[0];
  const int* cols = (const int*)d_in[1];
  const float* vals = (const float*)d_in[2];
  const float* X0 = (const float*)d_in[3];
  const float* W0 = (const float*)d_in[4];
  const float* W1 = (const float*)d_in[5];
  const int nnz = in_sizes[0];
  float* out = (float*)d_out;

  const int gemm_blocks = ((NNODES + 63) / 64) * 2;

  // fp16 CSR-path workspace (4 B elems):
  // pair[2*nnz int2] | Yeh[E*16 uint4] (bkt_items staging alias) |
  // Xh[N*16 uint4] | Pnh[N*16 uint4] | dvis[N] | dein[E] | off[NKEYS+1] |
  // bucket_cur[NB] | bucket_base[NB+1]
  size_t bkt_cap = (size_t)NB_E * CAP_E + (size_t)NB_N * CAP_N;  // entries
  size_t ye_elems = (size_t)NEDGES * 64;
  size_t xh_elems = (size_t)NNODES * 64;
  size_t elems = 4 * (size_t)nnz + ye_elems + 2 * xh_elems + NNODES + NEDGES +
                 (NKEYS + 1) + NB + (NB + 1);
  size_t need = elems * 4;
  bool bkt_fits = 2 * bkt_cap <= ye_elems;  // staging aliases Yeh

  if (ws_size >= need && bkt_fits && (size_t)2 * nnz <= bkt_cap) {
    int2* pair = (int2*)d_ws;
    uint4* Yeh = (uint4*)(pair + 2 * (size_t)nnz);
    int2* bkt_items = (int2*)Yeh;  // preprocessing alias
    uint4* Xh = Yeh + (size_t)NEDGES * 16;
    uint4* Pnh = Xh + (size_t)NNODES * 16;
    float* dvis = (float*)(Pnh + (size_t)NNODES * 16);
    float* dein = dvis + NNODES;
    int* off = (int*)(dein + NEDGES);
    int* bucket_cur = off + NKEYS + 1;
    int* bucket_base = bucket_cur + NB;

    hipMemsetAsync(bucket_cur, 0, NB * sizeof(int), stream);
    partition_kernel<<<(nnz + PART_CHUNK - 1) / PART_CHUNK, PART_THREADS, 0,
                       stream>>>(rows, cols, vals, bucket_cur, bkt_items, nnz);
    bucket_scan_kernel<<<1, 1024, 0, stream>>>(bucket_cur, bucket_base);
    place_kernel<<<NB, 256, 0, stream>>>(bucket_base, bucket_cur, bkt_items,
                                         off, pair, dein, dvis);
    scalex_h_kernel<<<(NNODES * 32 + 255) / 256, 256, 0, stream>>>(
        X0, dvis, (uint2*)Xh);

    const int eg_blocks = (NEDGES + 15) / 16;
    const int ng_blocks = (NNODES + 15) / 16;

    // layer 1
    gather_hh_kernel<<<eg_blocks, 256, 0, stream>>>(Xh, Yeh, off, pair, dein,
                                                    NEDGES);
    gather_hh_kernel<<<ng_blocks, 256, 0, stream>>>(Yeh, Pnh, off + NEDGES,
                                                    pair, dvis, NNODES);
    gemm_h_kernel<<<gemm_blocks, 256, 0, stream>>>(Pnh, dvis, W0, Xh, 1);

    // layer 2
    gather_hh_kernel<<<eg_blocks, 256, 0, stream>>>(Xh, Yeh, off, pair, dein,
                                                    NEDGES);
    gather_hh_kernel<<<ng_blocks, 256, 0, stream>>>(Yeh, Pnh, off + NEDGES,
                                                    pair, dvis, NNODES);
    gemm_h_kernel<<<gemm_blocks, 256, 0, stream>>>(Pnh, dvis, W1, out, 0);
    return;
  }

  // ---------- fallback: fp32 atomic-scatter path (row-major) ----------
  float* dv = (float*)d_ws;
  float* de = dv + NNODES;
  float* Ye = de + NEDGES;
  float* Pn = Ye + (size_t)NEDGES * HID;
  const int scat_blocks = (nnz + 7) / 8;

  hipMemsetAsync(dv, 0, (size_t)(NNODES + NEDGES) * sizeof(float), stream);
  deg_fb_kernel<<<(nnz + 255) / 256, 256, 0, stream>>>(rows, cols, vals, dv,
                                                       de, nnz);
  inv_kernel<<<(NNODES + NEDGES + 255) / 256, 256, 0, stream>>>(dv, de);

  hipMemsetAsync(Ye, 0, (size_t)NEDGES * HID * sizeof(float), stream);
  scatter_edge_kernel<<<scat_blocks, 256, 0, stream>>>(X0, Ye, rows, cols,
                                                       vals, dv, nnz);
  hipMemsetAsync(Pn, 0, (size_t)NNODES * HID * sizeof(float), stream);
  scatter_node_kernel<<<scat_blocks, 256, 0, stream>>>(Ye, Pn, rows, cols,
                                                       vals, de, nnz);
  gemm_rm_kernel<<<gemm_blocks, 256, 0, stream>>>(Pn, dv, W0, out, 2);

  hipMemsetAsync(Ye, 0, (size_t)NEDGES * HID * sizeof(float), stream);
  scatter_edge_kernel<<<scat_blocks, 256, 0, stream>>>(out, Ye, rows, cols,
                                                       vals, dv, nnz);
  hipMemsetAsync(Pn, 0, (size_t)NNODES * HID * sizeof(float), stream);
  scatter_node_kernel<<<scat_blocks, 256, 0, stream>>>(Ye, Pn, rows, cols,
                                                       vals, de, nnz);
  gemm_rm_kernel<<<gemm_blocks, 256, 0, stream>>>(Pn, dv, W1, out, 0);
}

// Round 17
// 288.064 us; speedup vs baseline: 1.1134x; 1.0047x over previous
//
#include <hip/hip_runtime.h>
#include <hip/hip_fp16.h>
#include <math.h>

#define NNODES 50000
#define NEDGES 100000
#define HID 128
#define NKEYS (NEDGES + NNODES)  // edge keys then node keys

// bucket decomposition: 256 keys per bucket
#define NB_E ((NEDGES + 255) >> 8)  // 391
#define NB_N ((NNODES + 255) >> 8)  // 196
#define NB (NB_E + NB_N)            // 587
#define CAP_E 3072                  // staging capacity per edge bucket
#define CAP_N 6144                  // staging capacity per node bucket
#define PART_CHUNK 2048
#define PART_THREADS 512

__device__ __forceinline__ int region_start(int b) {
  return (b < NB_E) ? b * CAP_E : NB_E * CAP_E + (b - NB_E) * CAP_N;
}

// zero bucket_cur without the runtime's fill kernel
__global__ __launch_bounds__(1024) void zero_kernel(int* __restrict__ p, int n) {
  int i = threadIdx.x;
  if (i < n) p[i] = 0;
}

// ===========================================================================
// partition: per-block LDS hist -> reserve in fixed-capacity bucket regions
// item.x = (key_low8 << 18) | neighbor(17b), item.y = val bits
// bucket_cur (zero-init) accumulates per-bucket counts.
// 512 threads/block: extra waves hide scattered-write latency.
// ===========================================================================
__global__ __launch_bounds__(PART_THREADS) void partition_kernel(
    const int* __restrict__ rows, const int* __restrict__ cols,
    const float* __restrict__ vals, int* __restrict__ bucket_cur,
    int2* __restrict__ bkt_items, int nnz) {
  __shared__ int cnt[NB];
  __shared__ int wbase[NB];
  for (int k = threadIdx.x; k < NB; k += PART_THREADS) cnt[k] = 0;
  __syncthreads();
  int start = blockIdx.x * PART_CHUNK;
  int end = start + PART_CHUNK;
  if (end > nnz) end = nnz;
  for (int i = start + threadIdx.x; i < end; i += PART_THREADS) {
    atomicAdd(&cnt[cols[i] >> 8], 1);
    atomicAdd(&cnt[NB_E + (rows[i] >> 8)], 1);
  }
  __syncthreads();
  for (int k = threadIdx.x; k < NB; k += PART_THREADS) {
    int c = cnt[k];
    wbase[k] = c ? region_start(k) + atomicAdd(&bucket_cur[k], c) : 0;
    cnt[k] = 0;
  }
  __syncthreads();
  for (int i = start + threadIdx.x; i < end; i += PART_THREADS) {
    int c = cols[i], r = rows[i];
    int v = __float_as_int(vals[i]);
    int be = c >> 8;
    int p = wbase[be] + atomicAdd(&cnt[be], 1);
    bkt_items[p] = make_int2(((c & 255) << 18) | r, v);
    int bn = NB_E + (r >> 8);
    int q = wbase[bn] + atomicAdd(&cnt[bn], 1);
    bkt_items[q] = make_int2(((r & 255) << 18) | c, v);
  }
}

// exclusive scan of NB bucket counts -> dense bases. one block.
__global__ __launch_bounds__(1024) void bucket_scan_kernel(
    const int* __restrict__ bucket_cur, int* __restrict__ bucket_base) {
  int t = threadIdx.x;
  int lane = t & 63, wid = t >> 6;
  int x = (t < NB) ? bucket_cur[t] : 0;
  int incl = x;
#pragma unroll
  for (int d = 1; d < 64; d <<= 1) {
    int tt = __shfl_up(incl, d, 64);
    if (lane >= d) incl += tt;
  }
  __shared__ int ws[16];
  if (lane == 63) ws[wid] = incl;
  __syncthreads();
  int woff = 0;
  for (int k = 0; k < wid; ++k) woff += ws[k];
  int excl = woff + incl - x;
  if (t < NB) bucket_base[t] = excl;
  if (t == NB - 1) bucket_base[NB] = excl + x;  // == 2*nnz
}

// ===========================================================================
// place v2: one block per bucket; caches staged region in LDS (<= CAP_N
// items = 48 KB), per-key LDS hist+scan (+ fused degree sums); writes dense
// off[], pair[], dein/dvis.
// ===========================================================================
__global__ __launch_bounds__(256) void place_kernel(
    const int* __restrict__ bucket_base, const int* __restrict__ bucket_cur,
    const int2* __restrict__ bkt_items, int* __restrict__ off,
    int2* __restrict__ pair, float* __restrict__ dein,
    float* __restrict__ dvis) {
  __shared__ int2 items[CAP_N];  // 48 KB
  __shared__ int kcnt[256];
  __shared__ float ksum[256];
  __shared__ int kbase[256];
  __shared__ int ws[4];
  int b = blockIdx.x;
  int rs = region_start(b);
  int cntb = bucket_cur[b];
  int s = bucket_base[b];
  int t = threadIdx.x;
  kcnt[t] = 0;
  ksum[t] = 0.f;
  __syncthreads();
  for (int j = t; j < cntb; j += 256) {
    int2 it = bkt_items[rs + j];
    items[j] = it;
    int k = it.x >> 18;
    atomicAdd(&kcnt[k], 1);
    atomicAdd(&ksum[k], __int_as_float(it.y));
  }
  __syncthreads();
  int x = kcnt[t];
  int lane = t & 63, wid = t >> 6;
  int incl = x;
#pragma unroll
  for (int d = 1; d < 64; d <<= 1) {
    int tt = __shfl_up(incl, d, 64);
    if (lane >= d) incl += tt;
  }
  if (lane == 63) ws[wid] = incl;
  __syncthreads();
  int woff = 0;
  for (int k = 0; k < wid; ++k) woff += ws[k];
  int excl = woff + incl - x;
  kbase[t] = s + excl;
  float sum = fmaxf(ksum[t], 1e-6f);
  if (b < NB_E) {
    int kglob = (b << 8) | t;
    if (kglob < NEDGES) {
      off[kglob] = s + excl;
      dein[kglob] = 1.0f / sum;
    }
  } else {
    int kglob = ((b - NB_E) << 8) | t;
    if (kglob < NNODES) {
      off[NEDGES + kglob] = s + excl;
      dvis[kglob] = rsqrtf(sum);
    }
  }
  if (b == NB - 1 && t == 0) off[NKEYS] = s + cntb;
  __syncthreads();
  kcnt[t] = 0;
  __syncthreads();
  for (int j = t; j < cntb; j += 256) {
    int2 it = items[j];
    int k = it.x >> 18;
    int pos = kbase[k] + atomicAdd(&kcnt[k], 1);
    pair[pos] = make_int2(it.x & 0x3FFFF, it.y);
  }
}

// ===========================================================================
// scalex_h: Xh (fp16 row-major) = dvis * X0. One thread per float4 (4 elems).
// ===========================================================================
__global__ __launch_bounds__(256) void scalex_h_kernel(
    const float* __restrict__ X, const float* __restrict__ dvis,
    uint2* __restrict__ Yh) {
  int i = blockIdx.x * 256 + threadIdx.x;
  if (i >= NNODES * 32) return;
  float s = dvis[i >> 5];
  float4 v = reinterpret_cast<const float4*>(X)[i];
  __half2 a = __float22half2_rn(make_float2(s * v.x, s * v.y));
  __half2 b = __float22half2_rn(make_float2(s * v.z, s * v.w));
  uint2 o;
  o.x = *reinterpret_cast<unsigned*>(&a);
  o.y = *reinterpret_cast<unsigned*>(&b);
  Yh[i] = o;
}

// ===========================================================================
// gather v7 (fp16): ONE SEGMENT PER 16-LANE GROUP (4 segments/wave).
// Group's 16 lanes read the full 256 B fp16 row as uint4; 2-deep unroll
// keeps 2 rows/group (8/wave) in flight. fp32 accumulate; NO cross-group
// shuffles; all 16 lanes write the output row directly.
// ===========================================================================
__global__ __launch_bounds__(256) void gather_hh_kernel(
    const uint4* __restrict__ src, uint4* __restrict__ dst,
    const int* __restrict__ off, const int2* __restrict__ pair,
    const float* __restrict__ seg_scale, int nseg) {
  int e = blockIdx.x * 16 + (threadIdx.x >> 4);
  if (e >= nseg) return;
  int li = threadIdx.x & 15;
  int s = off[e], t = off[e + 1];
  float acc[8] = {0.f, 0.f, 0.f, 0.f, 0.f, 0.f, 0.f, 0.f};
  int j = s;
  for (; j + 1 < t; j += 2) {
    int2 p0 = pair[j], p1 = pair[j + 1];
    float w0 = __int_as_float(p0.y), w1 = __int_as_float(p1.y);
    uint4 u0 = src[(size_t)p0.x * 16 + li];
    uint4 u1 = src[(size_t)p1.x * 16 + li];
    float2 f0 = __half22float2(*reinterpret_cast<__half2*>(&u0.x));
    float2 f1 = __half22float2(*reinterpret_cast<__half2*>(&u0.y));
    float2 f2 = __half22float2(*reinterpret_cast<__half2*>(&u0.z));
    float2 f3 = __half22float2(*reinterpret_cast<__half2*>(&u0.w));
    acc[0] = fmaf(w0, f0.x, acc[0]); acc[1] = fmaf(w0, f0.y, acc[1]);
    acc[2] = fmaf(w0, f1.x, acc[2]); acc[3] = fmaf(w0, f1.y, acc[3]);
    acc[4] = fmaf(w0, f2.x, acc[4]); acc[5] = fmaf(w0, f2.y, acc[5]);
    acc[6] = fmaf(w0, f3.x, acc[6]); acc[7] = fmaf(w0, f3.y, acc[7]);
    float2 g0 = __half22float2(*reinterpret_cast<__half2*>(&u1.x));
    float2 g1 = __half22float2(*reinterpret_cast<__half2*>(&u1.y));
    float2 g2 = __half22float2(*reinterpret_cast<__half2*>(&u1.z));
    float2 g3 = __half22float2(*reinterpret_cast<__half2*>(&u1.w));
    acc[0] = fmaf(w1, g0.x, acc[0]); acc[1] = fmaf(w1, g0.y, acc[1]);
    acc[2] = fmaf(w1, g1.x, acc[2]); acc[3] = fmaf(w1, g1.y, acc[3]);
    acc[4] = fmaf(w1, g2.x, acc[4]); acc[5] = fmaf(w1, g2.y, acc[5]);
    acc[6] = fmaf(w1, g3.x, acc[6]); acc[7] = fmaf(w1, g3.y, acc[7]);
  }
  if (j < t) {
    int2 p0 = pair[j];
    float w0 = __int_as_float(p0.y);
    uint4 u0 = src[(size_t)p0.x * 16 + li];
    float2 f0 = __half22float2(*reinterpret_cast<__half2*>(&u0.x));
    float2 f1 = __half22float2(*reinterpret_cast<__half2*>(&u0.y));
    float2 f2 = __half22float2(*reinterpret_cast<__half2*>(&u0.z));
    float2 f3 = __half22float2(*reinterpret_cast<__half2*>(&u0.w));
    acc[0] = fmaf(w0, f0.x, acc[0]); acc[1] = fmaf(w0, f0.y, acc[1]);
    acc[2] = fmaf(w0, f1.x, acc[2]); acc[3] = fmaf(w0, f1.y, acc[3]);
    acc[4] = fmaf(w0, f2.x, acc[4]); acc[5] = fmaf(w0, f2.y, acc[5]);
    acc[6] = fmaf(w0, f3.x, acc[6]); acc[7] = fmaf(w0, f3.y, acc[7]);
  }
  float sc = seg_scale ? seg_scale[e] : 1.0f;
  __half2 h0 = __float22half2_rn(make_float2(sc * acc[0], sc * acc[1]));
  __half2 h1 = __float22half2_rn(make_float2(sc * acc[2], sc * acc[3]));
  __half2 h2 = __float22half2_rn(make_float2(sc * acc[4], sc * acc[5]));
  __half2 h3 = __float22half2_rn(make_float2(sc * acc[6], sc * acc[7]));
  uint4 o;
  o.x = *reinterpret_cast<unsigned*>(&h0);
  o.y = *reinterpret_cast<unsigned*>(&h1);
  o.z = *reinterpret_cast<unsigned*>(&h2);
  o.w = *reinterpret_cast<unsigned*>(&h3);
  dst[(size_t)e * 16 + li] = o;
}

// ===========================================================================
// GEMM (fp16 X rows): acc = Pnh[n,:] @ W^T[:, j0:j0+64]
// Pnh already carries the propagate dvis scale (node-gather epilogue).
// mode 0: acc -> fp32 d_out | mode 1: dvis*relu(acc) -> fp16 Xh (layer2 src)
// ===========================================================================
__device__ __forceinline__ void cvt8(uint4 u, float* f) {
  float2 a = __half22float2(*reinterpret_cast<__half2*>(&u.x));
  float2 b = __half22float2(*reinterpret_cast<__half2*>(&u.y));
  float2 c = __half22float2(*reinterpret_cast<__half2*>(&u.z));
  float2 d = __half22float2(*reinterpret_cast<__half2*>(&u.w));
  f[0] = a.x; f[1] = a.y; f[2] = b.x; f[3] = b.y;
  f[4] = c.x; f[5] = c.y; f[6] = d.x; f[7] = d.y;
}

__global__ __launch_bounds__(256) void gemm_h_kernel(
    const uint4* __restrict__ Pnh, const float* __restrict__ dvis,
    const float* __restrict__ W, void* __restrict__ out_v, int mode) {
  __shared__ float WT[128 * 64];  // 32 KB
  int t = threadIdx.x;
  int jb = blockIdx.x & 1;
  int rb = blockIdx.x >> 1;
  int j0 = jb << 6;
  {
    int K = t & 31;
    int Jb = t >> 5;
#pragma unroll
    for (int p = 0; p < 2; ++p) {
      int J = Jb + (p << 3);
      const float* Wb = W + (size_t)(j0 + 4 * J) * 128 + 4 * K;
      float4 g0 = *reinterpret_cast<const float4*>(Wb);
      float4 g1 = *reinterpret_cast<const float4*>(Wb + 128);
      float4 g2 = *reinterpret_cast<const float4*>(Wb + 256);
      float4 g3 = *reinterpret_cast<const float4*>(Wb + 384);
      const float* g0p = reinterpret_cast<const float*>(&g0);
      const float* g1p = reinterpret_cast<const float*>(&g1);
      const float* g2p = reinterpret_cast<const float*>(&g2);
      const float* g3p = reinterpret_cast<const float*>(&g3);
#pragma unroll
      for (int q = 0; q < 4; ++q) {
        int k = 4 * K + q;
        float4 hq = make_float4(g0p[q], g1p[q], g2p[q], g3p[q]);
        int slot = (J + k) & 15;
        *reinterpret_cast<float4*>(&WT[k * 64 + 4 * slot]) = hq;
      }
    }
  }
  __syncthreads();
  int u = t & 15;
  int rg = t >> 4;
  int rbase = rb * 64 + rg * 4;
  const float4* WT4 = reinterpret_cast<const float4*>(WT);
  float4 acc0 = make_float4(0.f, 0.f, 0.f, 0.f);
  float4 acc1 = acc0, acc2 = acc0, acc3 = acc0;
  int rr0 = rbase + 0; if (rr0 >= NNODES) rr0 = NNODES - 1;
  int rr1 = rbase + 1; if (rr1 >= NNODES) rr1 = NNODES - 1;
  int rr2 = rbase + 2; if (rr2 >= NNODES) rr2 = NNODES - 1;
  int rr3 = rbase + 3; if (rr3 >= NNODES) rr3 = NNODES - 1;
  const uint4* X0 = Pnh + (size_t)rr0 * 16;
  const uint4* X1 = Pnh + (size_t)rr1 * 16;
  const uint4* X2 = Pnh + (size_t)rr2 * 16;
  const uint4* X3 = Pnh + (size_t)rr3 * 16;
#pragma unroll 4
  for (int kk = 0; kk < 16; ++kk) {
    float x0f[8], x1f[8], x2f[8], x3f[8];
    cvt8(X0[kk], x0f);
    cvt8(X1[kk], x1f);
    cvt8(X2[kk], x2f);
    cvt8(X3[kk], x3f);
#pragma unroll
    for (int q = 0; q < 8; ++q) {
      int k = kk * 8 + q;
      float4 w4 = WT4[k * 16 + ((u + k) & 15)];
      acc0.x = fmaf(x0f[q], w4.x, acc0.x); acc0.y = fmaf(x0f[q], w4.y, acc0.y);
      acc0.z = fmaf(x0f[q], w4.z, acc0.z); acc0.w = fmaf(x0f[q], w4.w, acc0.w);
      acc1.x = fmaf(x1f[q], w4.x, acc1.x); acc1.y = fmaf(x1f[q], w4.y, acc1.y);
      acc1.z = fmaf(x1f[q], w4.z, acc1.z); acc1.w = fmaf(x1f[q], w4.w, acc1.w);
      acc2.x = fmaf(x2f[q], w4.x, acc2.x); acc2.y = fmaf(x2f[q], w4.y, acc2.y);
      acc2.z = fmaf(x2f[q], w4.z, acc2.z); acc2.w = fmaf(x2f[q], w4.w, acc2.w);
      acc3.x = fmaf(x3f[q], w4.x, acc3.x); acc3.y = fmaf(x3f[q], w4.y, acc3.y);
      acc3.z = fmaf(x3f[q], w4.z, acc3.z); acc3.w = fmaf(x3f[q], w4.w, acc3.w);
    }
  }
#pragma unroll
  for (int m = 0; m < 4; ++m) {
    int r = rbase + m;
    if (r >= NNODES) break;
    float4 a = (m == 0) ? acc0 : (m == 1) ? acc1 : (m == 2) ? acc2 : acc3;
    if (mode == 1) {
      float s = dvis[r];
      float4 o = make_float4(fmaxf(a.x, 0.f) * s, fmaxf(a.y, 0.f) * s,
                             fmaxf(a.z, 0.f) * s, fmaxf(a.w, 0.f) * s);
      __half2 ha = __float22half2_rn(make_float2(o.x, o.y));
      __half2 hb = __float22half2_rn(make_float2(o.z, o.w));
      uint2 ou;
      ou.x = *reinterpret_cast<unsigned*>(&ha);
      ou.y = *reinterpret_cast<unsigned*>(&hb);
      reinterpret_cast<uint2*>(out_v)[(size_t)r * 32 + (j0 >> 2) + u] = ou;
    } else {
      *reinterpret_cast<float4*>(
          &reinterpret_cast<float*>(out_v)[(size_t)r * 128 + j0 + 4 * u]) = a;
    }
  }
}

// ===========================================================================
// Fallback (atomic-scatter, row-major fp32) kernels — unused if ws suffices
// ===========================================================================
__global__ __launch_bounds__(256) void deg_fb_kernel(
    const int* __restrict__ rows, const int* __restrict__ cols,
    const float* __restrict__ vals, float* __restrict__ dv,
    float* __restrict__ de, int nnz) {
  int i = blockIdx.x * 256 + threadIdx.x;
  if (i >= nnz) return;
  float v = vals[i];
  unsafeAtomicAdd(&dv[rows[i]], v);
  unsafeAtomicAdd(&de[cols[i]], v);
}

__global__ __launch_bounds__(256) void inv_kernel(float* __restrict__ dv,
                                                  float* __restrict__ de) {
  int i = blockIdx.x * 256 + threadIdx.x;
  if (i < NNODES) {
    dv[i] = 1.0f / sqrtf(fmaxf(dv[i], 1e-6f));
  } else if (i < NNODES + NEDGES) {
    int j = i - NNODES;
    de[j] = 1.0f / fmaxf(de[j], 1e-6f);
  }
}

__global__ __launch_bounds__(256) void scatter_edge_kernel(
    const float* __restrict__ X, float* __restrict__ Ye,
    const int* __restrict__ rows, const int* __restrict__ cols,
    const float* __restrict__ vals, const float* __restrict__ dvis, int nnz) {
  int g = (blockIdx.x * 256 + threadIdx.x) >> 5;
  int lane = threadIdx.x & 31;
  if (g >= nnz) return;
  int r = rows[g], c = cols[g];
  float s = vals[g] * dvis[r];
  float4 x = reinterpret_cast<const float4*>(X)[(size_t)r * 32 + lane];
  float* dst = Ye + (size_t)c * HID + lane * 4;
  unsafeAtomicAdd(dst + 0, s * x.x);
  unsafeAtomicAdd(dst + 1, s * x.y);
  unsafeAtomicAdd(dst + 2, s * x.z);
  unsafeAtomicAdd(dst + 3, s * x.w);
}

__global__ __launch_bounds__(256) void scatter_node_kernel(
    const float* __restrict__ Ye, float* __restrict__ Yn,
    const int* __restrict__ rows, const int* __restrict__ cols,
    const float* __restrict__ vals, const float* __restrict__ dein, int nnz) {
  int g = (blockIdx.x * 256 + threadIdx.x) >> 5;
  int lane = threadIdx.x & 31;
  if (g >= nnz) return;
  int r = rows[g], c = cols[g];
  float s = vals[g] * dein[c];
  float4 y = reinterpret_cast<const float4*>(Ye)[(size_t)c * 32 + lane];
  float* dst = Yn + (size_t)r * HID + lane * 4;
  unsafeAtomicAdd(dst + 0, s * y.x);
  unsafeAtomicAdd(dst + 1, s * y.y);
  unsafeAtomicAdd(dst + 2, s * y.z);
  unsafeAtomicAdd(dst + 3, s * y.w);
}

// row-major fp32 GEMM for fallback. mode 2: relu(s*acc), mode 0: s*acc
__global__ __launch_bounds__(256) void gemm_rm_kernel(
    const float* __restrict__ Pn, const float* __restrict__ dvis,
    const float* __restrict__ W, float* __restrict__ out, int mode) {
  __shared__ float WT[128 * 64];
  int t = threadIdx.x;
  int jb = blockIdx.x & 1;
  int rb = blockIdx.x >> 1;
  int j0 = jb << 6;
  {
    int K = t & 31;
    int Jb = t >> 5;
#pragma unroll
    for (int p = 0; p < 2; ++p) {
      int J = Jb + (p << 3);
      const float* Wb = W + (size_t)(j0 + 4 * J) * 128 + 4 * K;
      float4 g0 = *reinterpret_cast<const float4*>(Wb);
      float4 g1 = *reinterpret_cast<const float4*>(Wb + 128);
      float4 g2 = *reinterpret_cast<const float4*>(Wb + 256);
      float4 g3 = *reinterpret_cast<const float4*>(Wb + 384);
      const float* g0p = reinterpret_cast<const float*>(&g0);
      const float* g1p = reinterpret_cast<const float*>(&g1);
      const float* g2p = reinterpret_cast<const float*>(&g2);
      const float* g3p = reinterpret_cast<const float*>(&g3);
#pragma unroll
      for (int q = 0; q < 4; ++q) {
        int k = 4 * K + q;
        float4 hq = make_float4(g0p[q], g1p[q], g2p[q], g3p[q]);
        int slot = (J + k) & 15;
        *reinterpret_cast<float4*>(&WT[k * 64 + 4 * slot]) = hq;
      }
    }
  }
  __syncthreads();
  int u = t & 15;
  int rg = t >> 4;
  int rbase = rb * 64 + rg * 4;
  const float4* WT4 = reinterpret_cast<const float4*>(WT);
  float4 acc0 = make_float4(0.f, 0.f, 0.f, 0.f);
  float4 acc1 = acc0, acc2 = acc0, acc3 = acc0;
  int rr0 = rbase + 0; if (rr0 >= NNODES) rr0 = NNODES - 1;
  int rr1 = rbase + 1; if (rr1 >= NNODES) rr1 = NNODES - 1;
  int rr2 = rbase + 2; if (rr2 >= NNODES) rr2 = NNODES - 1;
  int rr3 = rbase + 3; if (rr3 >= NNODES) rr3 = NNODES - 1;
  const float4* X0 = reinterpret_cast<const float4*>(Pn + (size_t)rr0 * 128);
  const float4* X1 = reinterpret_cast<const float4*>(Pn + (size_t)rr1 * 128);
  const float4* X2 = reinterpret_cast<const float4*>(Pn + (size_t)rr2 * 128);
  const float4* X3 = reinterpret_cast<const float4*>(Pn + (size_t)rr3 * 128);
#pragma unroll 4
  for (int kk = 0; kk < 32; ++kk) {
    float4 x0 = X0[kk], x1 = X1[kk], x2 = X2[kk], x3 = X3[kk];
    const float* x0p = reinterpret_cast<const float*>(&x0);
    const float* x1p = reinterpret_cast<const float*>(&x1);
    const float* x2p = reinterpret_cast<const float*>(&x2);
    const float* x3p = reinterpret_cast<const float*>(&x3);
#pragma unroll
    for (int q = 0; q < 4; ++q) {
      int k = 4 * kk + q;
      float4 w4 = WT4[k * 16 + ((u + k) & 15)];
      acc0.x = fmaf(x0p[q], w4.x, acc0.x); acc0.y = fmaf(x0p[q], w4.y, acc0.y);
      acc0.z = fmaf(x0p[q], w4.z, acc0.z); acc0.w = fmaf(x0p[q], w4.w, acc0.w);
      acc1.x = fmaf(x1p[q], w4.x, acc1.x); acc1.y = fmaf(x1p[q], w4.y, acc1.y);
      acc1.z = fmaf(x1p[q], w4.z, acc1.z); acc1.w = fmaf(x1p[q], w4.w, acc1.w);
      acc2.x = fmaf(x2p[q], w4.x, acc2.x); acc2.y = fmaf(x2p[q], w4.y, acc2.y);
      acc2.z = fmaf(x2p[q], w4.z, acc2.z); acc2.w = fmaf(x2p[q], w4.w, acc2.w);
      acc3.x = fmaf(x3p[q], w4.x, acc3.x); acc3.y = fmaf(x3p[q], w4.y, acc3.y);
      acc3.z = fmaf(x3p[q], w4.z, acc3.z); acc3.w = fmaf(x3p[q], w4.w, acc3.w);
    }
  }
#pragma unroll
  for (int m = 0; m < 4; ++m) {
    int r = rbase + m;
    if (r >= NNODES) break;
    float4 a = (m == 0) ? acc0 : (m == 1) ? acc1 : (m == 2) ? acc2 : acc3;
    float s = dvis[r];
    float4 o = make_float4(s * a.x, s * a.y, s * a.z, s * a.w);
    if (mode == 2) {
      o.x = fmaxf(o.x, 0.f); o.y = fmaxf(o.y, 0.f);
      o.z = fmaxf(o.z, 0.f); o.w = fmaxf(o.w, 0.f);
    }
    *reinterpret_cast<float4*>(&out[(size_t)r * 128 + j0 + 4 * u]) = o;
  }
}

// ===========================================================================
extern "C" void kernel_launch(void* const* d_in, const int* in_sizes, int n_in,
                              void* d_out, int out_size, void* d_ws,
                              size_t ws_size, hipStream_t stream) {
  const int* rows = (const int*)d_in[0];
  const int* cols = (const int*)d_in[1];
  const float* vals = (const float*)d_in[2];
  const float* X0 = (const float*)d_in[3];
  const float* W0 = (const float*)d_in[4];
  const float* W1 = (const float*)d_in[5];
  const int nnz = in_sizes[0];
  float* out = (float*)d_out;

  const int gemm_blocks = ((NNODES + 63) / 64) * 2;

  // fp16 CSR-path workspace (4 B elems):
  // pair[2*nnz int2] | Yeh[E*16 uint4] (bkt_items staging alias) |
  // Xh[N*16 uint4] | Pnh[N*16 uint4] | dvis[N] | dein[E] | off[NKEYS+1] |
  // bucket_cur[NB] | bucket_base[NB+1]
  size_t bkt_cap = (size_t)NB_E * CAP_E + (size_t)NB_N * CAP_N;  // entries
  size_t ye_elems = (size_t)NEDGES * 64;
  size_t xh_elems = (size_t)NNODES * 64;
  size_t elems = 4 * (size_t)nnz + ye_elems + 2 * xh_elems + NNODES + NEDGES +
                 (NKEYS + 1) + NB + (NB + 1);
  size_t need = elems * 4;
  bool bkt_fits = 2 * bkt_cap <= ye_elems;  // staging aliases Yeh

  if (ws_size >= need && bkt_fits && (size_t)2 * nnz <= bkt_cap) {
    int2* pair = (int2*)d_ws;
    uint4* Yeh = (uint4*)(pair + 2 * (size_t)nnz);
    int2* bkt_items = (int2*)Yeh;  // preprocessing alias
    uint4* Xh = Yeh + (size_t)NEDGES * 16;
    uint4* Pnh = Xh + (size_t)NNODES * 16;
    float* dvis = (float*)(Pnh + (size_t)NNODES * 16);
    float* dein = dvis + NNODES;
    int* off = (int*)(dein + NEDGES);
    int* bucket_cur = off + NKEYS + 1;
    int* bucket_base = bucket_cur + NB;

    zero_kernel<<<1, 1024, 0, stream>>>(bucket_cur, NB);
    partition_kernel<<<(nnz + PART_CHUNK - 1) / PART_CHUNK, PART_THREADS, 0,
                       stream>>>(rows, cols, vals, bucket_cur, bkt_items, nnz);
    bucket_scan_kernel<<<1, 1024, 0, stream>>>(bucket_cur, bucket_base);
    place_kernel<<<NB, 256, 0, stream>>>(bucket_base, bucket_cur, bkt_items,
                                         off, pair, dein, dvis);
    scalex_h_kernel<<<(NNODES * 32 + 255) / 256, 256, 0, stream>>>(
        X0, dvis, (uint2*)Xh);

    const int eg_blocks = (NEDGES + 15) / 16;
    const int ng_blocks = (NNODES + 15) / 16;

    // layer 1
    gather_hh_kernel<<<eg_blocks, 256, 0, stream>>>(Xh, Yeh, off, pair, dein,
                                                    NEDGES);
    gather_hh_kernel<<<ng_blocks, 256, 0, stream>>>(Yeh, Pnh, off + NEDGES,
                                                    pair, dvis, NNODES);
    gemm_h_kernel<<<gemm_blocks, 256, 0, stream>>>(Pnh, dvis, W0, Xh, 1);

    // layer 2
    gather_hh_kernel<<<eg_blocks, 256, 0, stream>>>(Xh, Yeh, off, pair, dein,
                                                    NEDGES);
    gather_hh_kernel<<<ng_blocks, 256, 0, stream>>>(Yeh, Pnh, off + NEDGES,
                                                    pair, dvis, NNODES);
    gemm_h_kernel<<<gemm_blocks, 256, 0, stream>>>(Pnh, dvis, W1, out, 0);
    return;
  }

  // ---------- fallback: fp32 atomic-scatter path (row-major) ----------
  float* dv = (float*)d_ws;
  float* de = dv + NNODES;
  float* Ye = de + NEDGES;
  float* Pn = Ye + (size_t)NEDGES * HID;
  const int scat_blocks = (nnz + 7) / 8;

  hipMemsetAsync(dv, 0, (size_t)(NNODES + NEDGES) * sizeof(float), stream);
  deg_fb_kernel<<<(nnz + 255) / 256, 256, 0, stream>>>(rows, cols, vals, dv,
                                                       de, nnz);
  inv_kernel<<<(NNODES + NEDGES + 255) / 256, 256, 0, stream>>>(dv, de);

  hipMemsetAsync(Ye, 0, (size_t)NEDGES * HID * sizeof(float), stream);
  scatter_edge_kernel<<<scat_blocks, 256, 0, stream>>>(X0, Ye, rows, cols,
                                                       vals, dv, nnz);
  hipMemsetAsync(Pn, 0, (size_t)NNODES * HID * sizeof(float), stream);
  scatter_node_kernel<<<scat_blocks, 256, 0, stream>>>(Ye, Pn, rows, cols,
                                                       vals, de, nnz);
  gemm_rm_kernel<<<gemm_blocks, 256, 0, stream>>>(Pn, dv, W0, out, 2);

  hipMemsetAsync(Ye, 0, (size_t)NEDGES * HID * sizeof(float), stream);
  scatter_edge_kernel<<<scat_blocks, 256, 0, stream>>>(out, Ye, rows, cols,
                                                       vals, dv, nnz);
  hipMemsetAsync(Pn, 0, (size_t)NNODES * HID * sizeof(float), stream);
  scatter_node_kernel<<<scat_blocks, 256, 0, stream>>>(Ye, Pn, rows, cols,
                                                       vals, de, nnz);
  gemm_rm_kernel<<<gemm_blocks, 256, 0, stream>>>(Pn, dv, W1, out, 0);
}